// Round 8
// baseline (200.157 us; speedup 1.0000x reference)
//
#include <hip/hip_runtime.h>

// ResidualAttentionBlock (MFMA, round 15): B=16, FIN=256, H=W=32 (N=1024),
// NH=8, FH=64, CIN=258, COUT=512. Inputs fp32. v_mfma_f32_16x16x32_bf16,
// fp32 accumulation.
//
// Round 15 (attn + one qkv constant):
//  - Round-14 verified: conflict-free Pl cells (11.5M->2.1M), attn 60us.
//    Remaining cap is TLP: grid 1024 blocks AND 32.8KB LDS both = 4 blocks/CU.
//  - attn q-tile 64: 4 waves x 16 q-rows (sub loop deleted), grid (128 bh,
//    16 qt) = 2048 blocks; LDS 24.0KB (Kl 8K + Vl 8K + Pl 8K) -> 6 blocks/CU
//    -> 24 waves/CU (1.5x TLP). Per-wave state halved; no forced bounds
//    (round-12 spill trap). XCD locality preserved (qt stride 128 = 0 mod 8).
//  - exp2 fold: K pre-scale now 0.125*log2e (qkv oscale), attn uses raw
//    v_exp_f32 -> deletes the hidden x*log2e mul in __expf (16 VALU/wave-iter).
//  - All verified pieces kept: swapped QK^T, cell Pl (write b64 2-way-free,
//    read b128 conflict-free), K/V XOR swizzle, setprio.

typedef unsigned short u16;
typedef unsigned int   u32;
typedef __attribute__((ext_vector_type(8))) short  short8;
typedef __attribute__((ext_vector_type(4))) float  float4_;

#define MFMA16(a, b, c) __builtin_amdgcn_mfma_f32_16x16x32_bf16(a, b, c, 0, 0, 0)

__device__ __forceinline__ float bf2f(u16 u) {
    union { u32 i; float f; } v; v.i = ((u32)u) << 16; return v.f;
}
__device__ __forceinline__ u16 f2bf(float f) {           // RNE
    union { float f; u32 i; } v; v.f = f;
    u32 r = v.i + 0x7FFFu + ((v.i >> 16) & 1u);
    return (u16)(r >> 16);
}
__device__ __forceinline__ float exp2_fast(float x) {    // 2^x (CDNA interlocked)
    float r;
    asm("v_exp_f32 %0, %1" : "=v"(r) : "v"(x));
    return r;
}

// ---------------------------------------------------------------------------
// prep: blocks [0,512) convert wq/wk/wv [512][258] fp32 -> wb [1536][256] bf16
//       blocks [512,1536) transpose x [b][256][1024] fp32 -> xT [b][1024][256]
// ---------------------------------------------------------------------------
__global__ __launch_bounds__(256) void prep(
    const float* __restrict__ wq, const float* __restrict__ wk,
    const float* __restrict__ wv, const float* __restrict__ x,
    u16* __restrict__ wb, u16* __restrict__ xT)
{
    __shared__ float Lt[64][65];
    const int bid = blockIdx.x;
    const int tid = threadIdx.x;
    if (bid < 512) {
        int i = bid * 256 + tid;
        int o = i >> 8, c = i & 255;
        size_t si = (size_t)o * 258 + c;
        wb[i]          = f2bf(wq[si]);
        wb[131072 + i] = f2bf(wk[si]);
        wb[262144 + i] = f2bf(wv[si]);
    } else {
        int r = bid - 512;
        int n0 = (r & 15) * 64, c0 = ((r >> 4) & 3) * 64, b = r >> 6;
#pragma unroll
        for (int p = 0; p < 4; ++p) {
            int c = p * 16 + (tid >> 4);
            int nn = (tid & 15) * 4;
            float4 v = *(const float4*)&x[((size_t)(b * 256) + c0 + c) * 1024 + n0 + nn];
            Lt[c][nn + 0] = v.x; Lt[c][nn + 1] = v.y;
            Lt[c][nn + 2] = v.z; Lt[c][nn + 3] = v.w;
        }
        __syncthreads();
#pragma unroll
        for (int p = 0; p < 4; ++p) {
            int n = p * 16 + (tid >> 4);
            int cc = (tid & 15) * 4;
            ushort4 st;
            st.x = f2bf(Lt[cc + 0][n]); st.y = f2bf(Lt[cc + 1][n]);
            st.z = f2bf(Lt[cc + 2][n]); st.w = f2bf(Lt[cc + 3][n]);
            *(ushort4*)&xT[((size_t)(b << 10) + n0 + n) * 256 + c0 + cc] = st;
        }
    }
}

// ---------------------------------------------------------------------------
// Fused QKV GEMM, 128x128 tile, BK=32. Grid (8 nt, 12 mt, 16 b).
// mt covers 128 rows of the combined [1536][256] weight: mat = mt>>2,
// heads h0=(mt&3)*2, h0+1. mat 0=Q token-major [bh][n][64]; mat 1=K
// (pre-scaled 0.125*log2e for exp2 softmax) token-major; mat 2=V d-major.
// ---------------------------------------------------------------------------
__global__ __launch_bounds__(256) void qkv_mfma(
    const u16* __restrict__ xT, const u16* __restrict__ wb,
    const float* __restrict__ wq, const float* __restrict__ wk,
    const float* __restrict__ wv,
    const float* __restrict__ bq, const float* __restrict__ bk,
    const float* __restrict__ bv,
    u16* __restrict__ qkvbuf)
{
    __shared__ u16 Wl[128][40];
    __shared__ u16 Tl[128][40];
    const int tid = threadIdx.x;
    const int lane = tid & 63, w = tid >> 6;
    const int quad = lane >> 4, m15 = lane & 15;
    const int n0 = blockIdx.x * 128, mt = blockIdx.y, b = blockIdx.z;
    const int mat = mt >> 2;
    const int m0 = mt * 128;                    // row in combined W
    const float* worig = (mat == 0) ? wq : ((mat == 1) ? wk : wv);
    const float* bias  = (mat == 0) ? bq : ((mat == 1) ? bk : bv);
    const float oscale = (mat == 1) ? 0.1803368801111204f : 1.0f;  // 0.125*log2(e)
    u16* outbuf = qkvbuf + (size_t)mat * 8388608;

    float4_ acc[2][8];
#pragma unroll
    for (int s = 0; s < 2; ++s)
#pragma unroll
        for (int t = 0; t < 8; ++t) acc[s][t] = (float4_){0, 0, 0, 0};

    const int row = tid >> 2, col8 = (tid & 3) * 8;   // 64 rows x 32 cols per pass

    for (int cc0 = 0; cc0 < 256; cc0 += 32) {
        __syncthreads();
#pragma unroll
        for (int rr = 0; rr < 128; rr += 64) {
            *(short8*)&Wl[row + rr][col8] =
                *(const short8*)(wb + (size_t)(m0 + row + rr) * 256 + cc0 + col8);
            *(short8*)&Tl[row + rr][col8] =
                *(const short8*)(xT + ((size_t)(b << 10) + n0 + row + rr) * 256 + cc0 + col8);
        }
        __syncthreads();
        short8 af[2];
#pragma unroll
        for (int s = 0; s < 2; ++s)
            af[s] = *(const short8*)&Wl[w * 32 + s * 16 + m15][quad * 8];
#pragma unroll
        for (int t = 0; t < 8; ++t) {
            short8 bf = *(const short8*)&Tl[t * 16 + m15][quad * 8];
#pragma unroll
            for (int s = 0; s < 2; ++s)
                acc[s][t] = MFMA16(af[s], bf, acc[s][t]);
        }
    }

    // epilogue: rank-2 pos + bias, scale, store. om = row within this mat's 512.
#pragma unroll
    for (int s = 0; s < 2; ++s) {
        float wg[4], wx[4], bi[4];
#pragma unroll
        for (int r = 0; r < 4; ++r) {
            int om = (mt & 3) * 128 + w * 32 + s * 16 + quad * 4 + r;
            wg[r] = worig[(size_t)om * 258 + 256];
            wx[r] = worig[(size_t)om * 258 + 257];
            bi[r] = bias[om];
        }
        const int h = (mt & 3) * 2 + ((w * 32 + s * 16) >> 6);
        const int dbase = ((w * 32 + s * 16) & 63) + quad * 4;
#pragma unroll
        for (int t = 0; t < 8; ++t) {
            int n = n0 + t * 16 + m15;
            float gy = -1.0f + 2.0f * (float)(n >> 5) / 31.0f;
            float gx = -1.0f + 2.0f * (float)(n & 31) / 31.0f;
            float v[4];
#pragma unroll
            for (int r = 0; r < 4; ++r)
                v[r] = (acc[s][t][r] + wg[r] * gy + wx[r] * gx + bi[r]) * oscale;
            if (mat != 2) {      // token-major [bh][n][64]
                ushort4 st;
                st.x = f2bf(v[0]); st.y = f2bf(v[1]);
                st.z = f2bf(v[2]); st.w = f2bf(v[3]);
                *(ushort4*)&outbuf[((size_t)(b * 8 + h) * 1024 + n) * 64 + dbase] = st;
            } else {             // d-major [bh][64][n]
#pragma unroll
                for (int r = 0; r < 4; ++r)
                    outbuf[((size_t)(b * 8 + h) * 64 + dbase + r) * 1024 + n] = f2bf(v[r]);
            }
        }
    }
}

// ---------------------------------------------------------------------------
// Attention (round 15): block = (bh, q-tile 64), 4 waves x 16 q-rows, 256 thr.
// Swapped QK^T (S^T = mfma(K, Q)); exp2 softmax (K pre-scaled with log2e);
// conflict-free Pl cells; l = 1 scalar + 2 shfl_xor. Output in-place over
// qbuf [bh][n][64]. Grid (128 bh, 16 qt) — same-bh blocks same XCD.
// LDS 24.0 KB -> 6 blocks/CU -> 24 waves/CU.
// ---------------------------------------------------------------------------
__global__ __launch_bounds__(256) void attn_mfma(
    u16* __restrict__ qbuf, const u16* __restrict__ kbuf,
    const u16* __restrict__ vbuf)
{
    __shared__ u16 Kl[64 * 64];      // [kt][d], elem(kt,d) at kt*64 + (d ^ ((kt&7)<<3))
    __shared__ u16 Vl[64 * 64];      // V^T [d][kt], elem(d,kt) at d*64 + (kt ^ ((d&7)<<3))
    __shared__ u16 Pl[4][8][16][8];  // per-wave P^T cells: [w][pair][col=q'][8 kt]

    const int tid = threadIdx.x;
    const int lane = tid & 63, w = tid >> 6;
    const int quad = lane >> 4, m15 = lane & 15;
    const int bh = blockIdx.x;
    const int q0 = blockIdx.y * 64;
    u16* qb = qbuf + (size_t)bh * 65536;
    const u16* kb = kbuf + (size_t)bh * 65536;   // [1024 n][64 d]
    const u16* vb = vbuf + (size_t)bh * 65536;   // [64 d][1024 n]

    // Q frags (B-operand): wave w owns q rows q0 + w*16 + [0,16)
    short8 qf[2];
    {
        const u16* qr = qb + (size_t)(q0 + w * 16 + m15) * 64 + quad * 8;
        qf[0] = *(const short8*)qr;
        qf[1] = *(const short8*)(qr + 32);
    }

    float4_ O[4];                    // O^T tiles
    float lp = 0.0f;                 // per-lane partial l
#pragma unroll
    for (int t = 0; t < 4; ++t) O[t] = (float4_){0, 0, 0, 0};

    const int row = tid >> 3, c8 = (tid & 7) * 8;
    const int stsw = c8 ^ ((row & 7) << 3);       // K/V staging col swizzle (u16)
    const int rdsw = (m15 & 7) << 3;              // K/V fragment-read col XOR (u16)

    for (int kt0 = 0; kt0 < 1024; kt0 += 64) {
        __syncthreads();
#pragma unroll
        for (int rr = 0; rr < 64; rr += 32) {
            *(short8*)&Kl[(row + rr) * 64 + stsw] =
                *(const short8*)(kb + (size_t)(kt0 + row + rr) * 64 + c8);
            *(short8*)&Vl[(row + rr) * 64 + stsw] =
                *(const short8*)(vb + (size_t)(row + rr) * 1024 + kt0 + c8);
        }
        __syncthreads();

        // GEMM1 (swapped): lane holds S^T[kt=t*16+quad*4+r][q'=m15]
        float4_ S[4];
#pragma unroll
        for (int t = 0; t < 4; ++t) S[t] = (float4_){0, 0, 0, 0};
#pragma unroll
        for (int c = 0; c < 2; ++c) {
            short8 kf[4];
#pragma unroll
            for (int t = 0; t < 4; ++t)
                kf[t] = *(const short8*)&Kl[(t * 16 + m15) * 64 +
                                            ((c * 32 + quad * 8) ^ rdsw)];
            __builtin_amdgcn_s_setprio(1);
#pragma unroll
            for (int t = 0; t < 4; ++t)
                S[t] = MFMA16(kf[t], qf[c], S[t]);
            __builtin_amdgcn_s_setprio(0);
        }

        // exp2 + pack (cvt_pk) + b64 cell store; l partial
        {
            float lsum = 0.0f;
#pragma unroll
            for (int t = 0; t < 4; ++t) {
                float p0 = exp2_fast(S[t][0]);
                float p1 = exp2_fast(S[t][1]);
                float p2 = exp2_fast(S[t][2]);
                float p3 = exp2_fast(S[t][3]);
                u32 w0, w1;
                asm("v_cvt_pk_bf16_f32 %0, %1, %2" : "=v"(w0) : "v"(p0), "v"(p1));
                asm("v_cvt_pk_bf16_f32 %0, %1, %2" : "=v"(w1) : "v"(p2), "v"(p3));
                uint2 st; st.x = w0; st.y = w1;
                // cell(pair = t*2 + (quad>>1), col = m15), half = quad&1
                *(uint2*)&Pl[w][t * 2 + (quad >> 1)][m15][(quad & 1) * 4] = st;
                lsum += (p0 + p1) + (p2 + p3);
            }
            lp += lsum;
        }

        // GEMM2: O^T[d][q'] += V^T[d][kt] * P^T[kt][q']
#pragma unroll
        for (int c = 0; c < 2; ++c) {
            short8 av[4];
#pragma unroll
            for (int dt = 0; dt < 4; ++dt)
                av[dt] = *(const short8*)&Vl[(dt * 16 + m15) * 64 +
                                             ((c * 32 + quad * 8) ^ rdsw)];
            short8 bp = *(const short8*)&Pl[w][c * 4 + quad][m15][0];
            __builtin_amdgcn_s_setprio(1);
#pragma unroll
            for (int dt = 0; dt < 4; ++dt)
                O[dt] = MFMA16(av[dt], bp, O[dt]);
            __builtin_amdgcn_s_setprio(0);
        }
    }

    // l: sum the 4 quad partials for column q'=m15 (all lanes end with full l)
    {
        float v = lp;
        v += __shfl_xor(v, 16);
        v += __shfl_xor(v, 32);
        float linv = 1.0f / v;
        int n = q0 + w * 16 + m15;
#pragma unroll
        for (int dt = 0; dt < 4; ++dt) {
            ushort4 st;
            st.x = f2bf(O[dt][0] * linv);
            st.y = f2bf(O[dt][1] * linv);
            st.z = f2bf(O[dt][2] * linv);
            st.w = f2bf(O[dt][3] * linv);
            // in-place over qbuf: [bh][n][64]
            *(ushort4*)&qb[(size_t)n * 64 + dt * 16 + quad * 4] = st;
        }
    }
}

// ---------------------------------------------------------------------------
// Output projection + bias + residual. AO read from qbuf [bh][n][64].
// Grid (16 nt, 4 ft, 16 b).
// ---------------------------------------------------------------------------
__global__ __launch_bounds__(256) void proj_mfma(
    const u16* __restrict__ ao, const float* __restrict__ wo,
    const float* __restrict__ bo, const float* __restrict__ x,
    float* __restrict__ out)
{
    __shared__ u16 Wl[64][72];
    __shared__ u16 Tl[64][72];
    const int tid = threadIdx.x;
    const int lane = tid & 63, w = tid >> 6;
    const int quad = lane >> 4, m15 = lane & 15;
    const int n0 = blockIdx.x * 64, f0 = blockIdx.y * 64, b = blockIdx.z;

    float4_ acc[4] = {{0,0,0,0},{0,0,0,0},{0,0,0,0},{0,0,0,0}};
    const int row = tid >> 3, c8 = (tid & 7) * 8;

    for (int cc0 = 0; cc0 < 512; cc0 += 64) {
        __syncthreads();
        const int h = cc0 >> 6;
#pragma unroll
        for (int rr = 0; rr < 64; rr += 32) {
            const float* wsrc = wo + (size_t)(f0 + row + rr) * 512 + cc0 + c8;
            float4 v0 = *(const float4*)wsrc;
            float4 v1 = *(const float4*)(wsrc + 4);
            ushort4 s0, s1;
            s0.x = f2bf(v0.x); s0.y = f2bf(v0.y); s0.z = f2bf(v0.z); s0.w = f2bf(v0.w);
            s1.x = f2bf(v1.x); s1.y = f2bf(v1.y); s1.z = f2bf(v1.z); s1.w = f2bf(v1.w);
            *(ushort4*)&Wl[row + rr][c8]     = s0;
            *(ushort4*)&Wl[row + rr][c8 + 4] = s1;
            *(short8*)&Tl[row + rr][c8] =
                *(const short8*)(ao + ((size_t)((b << 3) + h) * 1024 + n0 + row + rr) * 64 + c8);
        }
        __syncthreads();
#pragma unroll
        for (int c = 0; c < 2; ++c) {
            short8 af = *(const short8*)&Wl[w * 16 + m15][c * 32 + quad * 8];
#pragma unroll
            for (int t = 0; t < 4; ++t) {
                short8 bf = *(const short8*)&Tl[t * 16 + m15][c * 32 + quad * 8];
                acc[t] = MFMA16(af, bf, acc[t]);
            }
        }
    }

    float bi[4];
#pragma unroll
    for (int r = 0; r < 4; ++r) bi[r] = bo[f0 + w * 16 + quad * 4 + r];
#pragma unroll
    for (int t = 0; t < 4; ++t) {
        int n = n0 + t * 16 + m15;
#pragma unroll
        for (int r = 0; r < 4; ++r) {
            int f = f0 + w * 16 + quad * 4 + r;
            size_t idx = ((size_t)(b * 256) + f) * 1024 + n;
            out[idx] = acc[t][r] + bi[r] + x[idx];
        }
    }
}

extern "C" void kernel_launch(void* const* d_in, const int* in_sizes, int n_in,
                              void* d_out, int out_size, void* d_ws, size_t ws_size,
                              hipStream_t stream) {
    const float* x  = (const float*)d_in[0];
    const float* wq = (const float*)d_in[1];
    const float* bq = (const float*)d_in[2];
    const float* wk = (const float*)d_in[3];
    const float* bk = (const float*)d_in[4];
    const float* wv = (const float*)d_in[5];
    const float* bv = (const float*)d_in[6];
    const float* wo = (const float*)d_in[7];
    const float* bo = (const float*)d_in[8];

    // ws layout (u16 elems), ~59.8 MiB used:
    //   qkvbuf: 3 x 8,388,608 (Q, K, V). attn writes AO in-place over Q.
    //   region: xT[4,194,304] + wb[393,216] — no aliasing with anything live.
    u16* qkvbuf = (u16*)d_ws;
    u16* region = qkvbuf + 3 * 8388608;
    u16* xT = region;
    u16* wb = region + 4194304;

    prep<<<1536, 256, 0, stream>>>(wq, wk, wv, x, wb, xT);

    qkv_mfma<<<dim3(8, 12, 16), 256, 0, stream>>>(
        xT, wb, wq, wk, wv, bq, bk, bv, qkvbuf);

    attn_mfma<<<dim3(128, 16), 256, 0, stream>>>(
        qkvbuf, qkvbuf + 8388608, qkvbuf + 16777216);

    proj_mfma<<<dim3(16, 4, 16), 256, 0, stream>>>(qkvbuf, wo, bo, x, (float*)d_out);
}

// Round 9
// 190.311 us; speedup vs baseline: 1.0517x; 1.0517x over previous
//
#include <hip/hip_runtime.h>

// ResidualAttentionBlock (MFMA, round 16): B=16, FIN=256, H=W=32 (N=1024),
// NH=8, FH=64, CIN=258, COUT=512. Inputs fp32. v_mfma_f32_16x16x32_bf16,
// fp32 accumulation.
//
// Round 16 (attn only; prep/qkv/proj = round 15):
//  - Round-15 post-mortem: q-tile 64 raised occupancy (39%) but doubled
//    K/V staging per FLOP (FETCH 51->87MB) -> net regression (60->64us).
//  - Synthesis: q-tile 128 (round-14 amortization) x 8 waves of 16 q-rows
//    (round-15 light per-wave state, measured 44 VGPR). 512 thr/block,
//    grid (128 bh, 8 qt) = 1024 blocks; LDS 32.8KB (Kl 8K+Vl 8K+Pl 16K)
//    -> 4 blocks/CU x 512 thr = 2048 thr/CU = HW max (2x round-14 TLP).
//    No forced launch_bounds second arg (round-12 spill trap).
//  - Kept: swapped QK^T, exp2 softmax (K pre-scaled 0.125*log2e in qkv),
//    conflict-free Pl cells, K/V XOR swizzle, XCD-local grid, setprio.

typedef unsigned short u16;
typedef unsigned int   u32;
typedef __attribute__((ext_vector_type(8))) short  short8;
typedef __attribute__((ext_vector_type(4))) float  float4_;

#define MFMA16(a, b, c) __builtin_amdgcn_mfma_f32_16x16x32_bf16(a, b, c, 0, 0, 0)

__device__ __forceinline__ float bf2f(u16 u) {
    union { u32 i; float f; } v; v.i = ((u32)u) << 16; return v.f;
}
__device__ __forceinline__ u16 f2bf(float f) {           // RNE
    union { float f; u32 i; } v; v.f = f;
    u32 r = v.i + 0x7FFFu + ((v.i >> 16) & 1u);
    return (u16)(r >> 16);
}
__device__ __forceinline__ float exp2_fast(float x) {    // 2^x
    float r;
    asm("v_exp_f32 %0, %1" : "=v"(r) : "v"(x));
    return r;
}

// ---------------------------------------------------------------------------
// prep: blocks [0,512) convert wq/wk/wv [512][258] fp32 -> wb [1536][256] bf16
//       blocks [512,1536) transpose x [b][256][1024] fp32 -> xT [b][1024][256]
// ---------------------------------------------------------------------------
__global__ __launch_bounds__(256) void prep(
    const float* __restrict__ wq, const float* __restrict__ wk,
    const float* __restrict__ wv, const float* __restrict__ x,
    u16* __restrict__ wb, u16* __restrict__ xT)
{
    __shared__ float Lt[64][65];
    const int bid = blockIdx.x;
    const int tid = threadIdx.x;
    if (bid < 512) {
        int i = bid * 256 + tid;
        int o = i >> 8, c = i & 255;
        size_t si = (size_t)o * 258 + c;
        wb[i]          = f2bf(wq[si]);
        wb[131072 + i] = f2bf(wk[si]);
        wb[262144 + i] = f2bf(wv[si]);
    } else {
        int r = bid - 512;
        int n0 = (r & 15) * 64, c0 = ((r >> 4) & 3) * 64, b = r >> 6;
#pragma unroll
        for (int p = 0; p < 4; ++p) {
            int c = p * 16 + (tid >> 4);
            int nn = (tid & 15) * 4;
            float4 v = *(const float4*)&x[((size_t)(b * 256) + c0 + c) * 1024 + n0 + nn];
            Lt[c][nn + 0] = v.x; Lt[c][nn + 1] = v.y;
            Lt[c][nn + 2] = v.z; Lt[c][nn + 3] = v.w;
        }
        __syncthreads();
#pragma unroll
        for (int p = 0; p < 4; ++p) {
            int n = p * 16 + (tid >> 4);
            int cc = (tid & 15) * 4;
            ushort4 st;
            st.x = f2bf(Lt[cc + 0][n]); st.y = f2bf(Lt[cc + 1][n]);
            st.z = f2bf(Lt[cc + 2][n]); st.w = f2bf(Lt[cc + 3][n]);
            *(ushort4*)&xT[((size_t)(b << 10) + n0 + n) * 256 + c0 + cc] = st;
        }
    }
}

// ---------------------------------------------------------------------------
// Fused QKV GEMM, 128x128 tile, BK=32. Grid (8 nt, 12 mt, 16 b).
// mt covers 128 rows of the combined [1536][256] weight: mat = mt>>2,
// heads h0=(mt&3)*2, h0+1. mat 0=Q token-major [bh][n][64]; mat 1=K
// (pre-scaled 0.125*log2e for exp2 softmax) token-major; mat 2=V d-major.
// ---------------------------------------------------------------------------
__global__ __launch_bounds__(256) void qkv_mfma(
    const u16* __restrict__ xT, const u16* __restrict__ wb,
    const float* __restrict__ wq, const float* __restrict__ wk,
    const float* __restrict__ wv,
    const float* __restrict__ bq, const float* __restrict__ bk,
    const float* __restrict__ bv,
    u16* __restrict__ qkvbuf)
{
    __shared__ u16 Wl[128][40];
    __shared__ u16 Tl[128][40];
    const int tid = threadIdx.x;
    const int lane = tid & 63, w = tid >> 6;
    const int quad = lane >> 4, m15 = lane & 15;
    const int n0 = blockIdx.x * 128, mt = blockIdx.y, b = blockIdx.z;
    const int mat = mt >> 2;
    const int m0 = mt * 128;                    // row in combined W
    const float* worig = (mat == 0) ? wq : ((mat == 1) ? wk : wv);
    const float* bias  = (mat == 0) ? bq : ((mat == 1) ? bk : bv);
    const float oscale = (mat == 1) ? 0.1803368801111204f : 1.0f;  // 0.125*log2(e)
    u16* outbuf = qkvbuf + (size_t)mat * 8388608;

    float4_ acc[2][8];
#pragma unroll
    for (int s = 0; s < 2; ++s)
#pragma unroll
        for (int t = 0; t < 8; ++t) acc[s][t] = (float4_){0, 0, 0, 0};

    const int row = tid >> 2, col8 = (tid & 3) * 8;   // 64 rows x 32 cols per pass

    for (int cc0 = 0; cc0 < 256; cc0 += 32) {
        __syncthreads();
#pragma unroll
        for (int rr = 0; rr < 128; rr += 64) {
            *(short8*)&Wl[row + rr][col8] =
                *(const short8*)(wb + (size_t)(m0 + row + rr) * 256 + cc0 + col8);
            *(short8*)&Tl[row + rr][col8] =
                *(const short8*)(xT + ((size_t)(b << 10) + n0 + row + rr) * 256 + cc0 + col8);
        }
        __syncthreads();
        short8 af[2];
#pragma unroll
        for (int s = 0; s < 2; ++s)
            af[s] = *(const short8*)&Wl[w * 32 + s * 16 + m15][quad * 8];
#pragma unroll
        for (int t = 0; t < 8; ++t) {
            short8 bf = *(const short8*)&Tl[t * 16 + m15][quad * 8];
#pragma unroll
            for (int s = 0; s < 2; ++s)
                acc[s][t] = MFMA16(af[s], bf, acc[s][t]);
        }
    }

    // epilogue: rank-2 pos + bias, scale, store. om = row within this mat's 512.
#pragma unroll
    for (int s = 0; s < 2; ++s) {
        float wg[4], wx[4], bi[4];
#pragma unroll
        for (int r = 0; r < 4; ++r) {
            int om = (mt & 3) * 128 + w * 32 + s * 16 + quad * 4 + r;
            wg[r] = worig[(size_t)om * 258 + 256];
            wx[r] = worig[(size_t)om * 258 + 257];
            bi[r] = bias[om];
        }
        const int h = (mt & 3) * 2 + ((w * 32 + s * 16) >> 6);
        const int dbase = ((w * 32 + s * 16) & 63) + quad * 4;
#pragma unroll
        for (int t = 0; t < 8; ++t) {
            int n = n0 + t * 16 + m15;
            float gy = -1.0f + 2.0f * (float)(n >> 5) / 31.0f;
            float gx = -1.0f + 2.0f * (float)(n & 31) / 31.0f;
            float v[4];
#pragma unroll
            for (int r = 0; r < 4; ++r)
                v[r] = (acc[s][t][r] + wg[r] * gy + wx[r] * gx + bi[r]) * oscale;
            if (mat != 2) {      // token-major [bh][n][64]
                ushort4 st;
                st.x = f2bf(v[0]); st.y = f2bf(v[1]);
                st.z = f2bf(v[2]); st.w = f2bf(v[3]);
                *(ushort4*)&outbuf[((size_t)(b * 8 + h) * 1024 + n) * 64 + dbase] = st;
            } else {             // d-major [bh][64][n]
#pragma unroll
                for (int r = 0; r < 4; ++r)
                    outbuf[((size_t)(b * 8 + h) * 64 + dbase + r) * 1024 + n] = f2bf(v[r]);
            }
        }
    }
}

// ---------------------------------------------------------------------------
// Attention (round 16): block = (bh, q-tile 128), 8 waves x 16 q-rows,
// 512 threads. Swapped QK^T; exp2 softmax; conflict-free Pl cells; l = 1
// scalar + 2 shfl_xor. Output in-place over qbuf [bh][n][64].
// Grid (128 bh, 8 qt). LDS 32.8KB -> 4 blocks/CU = 2048 thr/CU (HW max).
// ---------------------------------------------------------------------------
__global__ __launch_bounds__(512) void attn_mfma(
    u16* __restrict__ qbuf, const u16* __restrict__ kbuf,
    const u16* __restrict__ vbuf)
{
    __shared__ u16 Kl[64 * 64];      // [kt][d], elem(kt,d) at kt*64 + (d ^ ((kt&7)<<3))
    __shared__ u16 Vl[64 * 64];      // V^T [d][kt], elem(d,kt) at d*64 + (kt ^ ((d&7)<<3))
    __shared__ u16 Pl[8][8][16][8];  // per-wave P^T cells: [w][pair][col=q'][8 kt]

    const int tid = threadIdx.x;
    const int lane = tid & 63, w = tid >> 6;          // w in [0,8)
    const int quad = lane >> 4, m15 = lane & 15;
    const int bh = blockIdx.x;
    const int q0 = blockIdx.y * 128;
    u16* qb = qbuf + (size_t)bh * 65536;
    const u16* kb = kbuf + (size_t)bh * 65536;   // [1024 n][64 d]
    const u16* vb = vbuf + (size_t)bh * 65536;   // [64 d][1024 n]

    // Q frags (B-operand): wave w owns q rows q0 + w*16 + [0,16)
    short8 qf[2];
    {
        const u16* qr = qb + (size_t)(q0 + w * 16 + m15) * 64 + quad * 8;
        qf[0] = *(const short8*)qr;
        qf[1] = *(const short8*)(qr + 32);
    }

    float4_ O[4];                    // O^T tiles
    float lp = 0.0f;                 // per-lane partial l
#pragma unroll
    for (int t = 0; t < 4; ++t) O[t] = (float4_){0, 0, 0, 0};

    const int row = tid >> 3, c8 = (tid & 7) * 8;     // 512 thr cover 64 rows x 64 cols
    const int stsw = c8 ^ ((row & 7) << 3);           // K/V staging col swizzle (u16)
    const int rdsw = (m15 & 7) << 3;                  // K/V fragment-read col XOR (u16)

    for (int kt0 = 0; kt0 < 1024; kt0 += 64) {
        __syncthreads();
        *(short8*)&Kl[row * 64 + stsw] =
            *(const short8*)(kb + (size_t)(kt0 + row) * 64 + c8);
        *(short8*)&Vl[row * 64 + stsw] =
            *(const short8*)(vb + (size_t)row * 1024 + kt0 + c8);
        __syncthreads();

        // GEMM1 (swapped): lane holds S^T[kt=t*16+quad*4+r][q'=m15]
        float4_ S[4];
#pragma unroll
        for (int t = 0; t < 4; ++t) S[t] = (float4_){0, 0, 0, 0};
#pragma unroll
        for (int c = 0; c < 2; ++c) {
            short8 kf[4];
#pragma unroll
            for (int t = 0; t < 4; ++t)
                kf[t] = *(const short8*)&Kl[(t * 16 + m15) * 64 +
                                            ((c * 32 + quad * 8) ^ rdsw)];
            __builtin_amdgcn_s_setprio(1);
#pragma unroll
            for (int t = 0; t < 4; ++t)
                S[t] = MFMA16(kf[t], qf[c], S[t]);
            __builtin_amdgcn_s_setprio(0);
        }

        // exp2 + pack (cvt_pk) + b64 cell store; l partial
        {
            float lsum = 0.0f;
#pragma unroll
            for (int t = 0; t < 4; ++t) {
                float p0 = exp2_fast(S[t][0]);
                float p1 = exp2_fast(S[t][1]);
                float p2 = exp2_fast(S[t][2]);
                float p3 = exp2_fast(S[t][3]);
                u32 w0, w1;
                asm("v_cvt_pk_bf16_f32 %0, %1, %2" : "=v"(w0) : "v"(p0), "v"(p1));
                asm("v_cvt_pk_bf16_f32 %0, %1, %2" : "=v"(w1) : "v"(p2), "v"(p3));
                uint2 st; st.x = w0; st.y = w1;
                // cell(pair = t*2 + (quad>>1), col = m15), half = quad&1
                *(uint2*)&Pl[w][t * 2 + (quad >> 1)][m15][(quad & 1) * 4] = st;
                lsum += (p0 + p1) + (p2 + p3);
            }
            lp += lsum;
        }

        // GEMM2: O^T[d][q'] += V^T[d][kt] * P^T[kt][q']
#pragma unroll
        for (int c = 0; c < 2; ++c) {
            short8 av[4];
#pragma unroll
            for (int dt = 0; dt < 4; ++dt)
                av[dt] = *(const short8*)&Vl[(dt * 16 + m15) * 64 +
                                             ((c * 32 + quad * 8) ^ rdsw)];
            short8 bp = *(const short8*)&Pl[w][c * 4 + quad][m15][0];
            __builtin_amdgcn_s_setprio(1);
#pragma unroll
            for (int dt = 0; dt < 4; ++dt)
                O[dt] = MFMA16(av[dt], bp, O[dt]);
            __builtin_amdgcn_s_setprio(0);
        }
    }

    // l: sum the 4 quad partials for column q'=m15 (all lanes end with full l)
    {
        float v = lp;
        v += __shfl_xor(v, 16);
        v += __shfl_xor(v, 32);
        float linv = 1.0f / v;
        int n = q0 + w * 16 + m15;
#pragma unroll
        for (int dt = 0; dt < 4; ++dt) {
            ushort4 st;
            st.x = f2bf(O[dt][0] * linv);
            st.y = f2bf(O[dt][1] * linv);
            st.z = f2bf(O[dt][2] * linv);
            st.w = f2bf(O[dt][3] * linv);
            // in-place over qbuf: [bh][n][64]
            *(ushort4*)&qb[(size_t)n * 64 + dt * 16 + quad * 4] = st;
        }
    }
}

// ---------------------------------------------------------------------------
// Output projection + bias + residual. AO read from qbuf [bh][n][64].
// Grid (16 nt, 4 ft, 16 b).
// ---------------------------------------------------------------------------
__global__ __launch_bounds__(256) void proj_mfma(
    const u16* __restrict__ ao, const float* __restrict__ wo,
    const float* __restrict__ bo, const float* __restrict__ x,
    float* __restrict__ out)
{
    __shared__ u16 Wl[64][72];
    __shared__ u16 Tl[64][72];
    const int tid = threadIdx.x;
    const int lane = tid & 63, w = tid >> 6;
    const int quad = lane >> 4, m15 = lane & 15;
    const int n0 = blockIdx.x * 64, f0 = blockIdx.y * 64, b = blockIdx.z;

    float4_ acc[4] = {{0,0,0,0},{0,0,0,0},{0,0,0,0},{0,0,0,0}};
    const int row = tid >> 3, c8 = (tid & 7) * 8;

    for (int cc0 = 0; cc0 < 512; cc0 += 64) {
        __syncthreads();
        const int h = cc0 >> 6;
#pragma unroll
        for (int rr = 0; rr < 64; rr += 32) {
            const float* wsrc = wo + (size_t)(f0 + row + rr) * 512 + cc0 + c8;
            float4 v0 = *(const float4*)wsrc;
            float4 v1 = *(const float4*)(wsrc + 4);
            ushort4 s0, s1;
            s0.x = f2bf(v0.x); s0.y = f2bf(v0.y); s0.z = f2bf(v0.z); s0.w = f2bf(v0.w);
            s1.x = f2bf(v1.x); s1.y = f2bf(v1.y); s1.z = f2bf(v1.z); s1.w = f2bf(v1.w);
            *(ushort4*)&Wl[row + rr][c8]     = s0;
            *(ushort4*)&Wl[row + rr][c8 + 4] = s1;
            *(short8*)&Tl[row + rr][c8] =
                *(const short8*)(ao + ((size_t)((b << 3) + h) * 1024 + n0 + row + rr) * 64 + c8);
        }
        __syncthreads();
#pragma unroll
        for (int c = 0; c < 2; ++c) {
            short8 af = *(const short8*)&Wl[w * 16 + m15][c * 32 + quad * 8];
#pragma unroll
            for (int t = 0; t < 4; ++t) {
                short8 bf = *(const short8*)&Tl[t * 16 + m15][c * 32 + quad * 8];
                acc[t] = MFMA16(af, bf, acc[t]);
            }
        }
    }

    float bi[4];
#pragma unroll
    for (int r = 0; r < 4; ++r) bi[r] = bo[f0 + w * 16 + quad * 4 + r];
#pragma unroll
    for (int t = 0; t < 4; ++t) {
        int n = n0 + t * 16 + m15;
#pragma unroll
        for (int r = 0; r < 4; ++r) {
            int f = f0 + w * 16 + quad * 4 + r;
            size_t idx = ((size_t)(b * 256) + f) * 1024 + n;
            out[idx] = acc[t][r] + bi[r] + x[idx];
        }
    }
}

extern "C" void kernel_launch(void* const* d_in, const int* in_sizes, int n_in,
                              void* d_out, int out_size, void* d_ws, size_t ws_size,
                              hipStream_t stream) {
    const float* x  = (const float*)d_in[0];
    const float* wq = (const float*)d_in[1];
    const float* bq = (const float*)d_in[2];
    const float* wk = (const float*)d_in[3];
    const float* bk = (const float*)d_in[4];
    const float* wv = (const float*)d_in[5];
    const float* bv = (const float*)d_in[6];
    const float* wo = (const float*)d_in[7];
    const float* bo = (const float*)d_in[8];

    // ws layout (u16 elems), ~59.8 MiB used:
    //   qkvbuf: 3 x 8,388,608 (Q, K, V). attn writes AO in-place over Q.
    //   region: xT[4,194,304] + wb[393,216] — no aliasing with anything live.
    u16* qkvbuf = (u16*)d_ws;
    u16* region = qkvbuf + 3 * 8388608;
    u16* xT = region;
    u16* wb = region + 4194304;

    prep<<<1536, 256, 0, stream>>>(wq, wk, wv, x, wb, xT);

    qkv_mfma<<<dim3(8, 12, 16), 256, 0, stream>>>(
        xT, wb, wq, wk, wv, bq, bk, bv, qkvbuf);

    attn_mfma<<<dim3(128, 8), 512, 0, stream>>>(
        qkvbuf, qkvbuf + 8388608, qkvbuf + 16777216);

    proj_mfma<<<dim3(16, 4, 16), 256, 0, stream>>>(qkvbuf, wo, bo, x, (float*)d_out);
}

// Round 10
// 187.793 us; speedup vs baseline: 1.0658x; 1.0134x over previous
//
#include <hip/hip_runtime.h>

// ResidualAttentionBlock (MFMA, round 17): B=16, FIN=256, H=W=32 (N=1024),
// NH=8, FH=64, CIN=258, COUT=512. Inputs fp32. v_mfma_f32_16x16x32_bf16,
// fp32 accumulation.
//
// Round 17 (qkv + proj; attn/prep = round 16 best):
//  - attn is 55.6us of 190 total; qkv/proj (~12.9+4.3 GFLOP) carry the SAME
//    LDS defects attn had pre-round-9: padded [.][40]/[.][72] tiles with
//    m15-row/quad-col fragment reads = ~8-way bank aliasing (attn's verified
//    5.3M->1.1M fix). Transfer the proven recipe:
//  - qkv: BK 32->64, linear [128][64] tiles, col8 ^ ((row&7)<<3) swizzle on
//    both ds_write staging and fragment reads; 4 k-iters (half barriers).
//  - proj: linear [64][64] tiles + same swizzle; wo fp32->bf16 conversion via
//    v_cvt_pk_bf16_f32 (4 ops per 8 floats, vs 8 RNE f2bf ~32 ops) + single
//    b128 stage store.
//  - attn unchanged (round-16: 8 waves x 16 q-rows, swapped QK^T, exp2,
//    conflict-free Pl cells, K/V swizzle, XCD grid).

typedef unsigned short u16;
typedef unsigned int   u32;
typedef __attribute__((ext_vector_type(8))) short  short8;
typedef __attribute__((ext_vector_type(4))) float  float4_;

#define MFMA16(a, b, c) __builtin_amdgcn_mfma_f32_16x16x32_bf16(a, b, c, 0, 0, 0)

__device__ __forceinline__ float bf2f(u16 u) {
    union { u32 i; float f; } v; v.i = ((u32)u) << 16; return v.f;
}
__device__ __forceinline__ u16 f2bf(float f) {           // RNE
    union { float f; u32 i; } v; v.f = f;
    u32 r = v.i + 0x7FFFu + ((v.i >> 16) & 1u);
    return (u16)(r >> 16);
}
__device__ __forceinline__ float exp2_fast(float x) {    // 2^x
    float r;
    asm("v_exp_f32 %0, %1" : "=v"(r) : "v"(x));
    return r;
}
__device__ __forceinline__ u32 cvtpk_bf16(float lo, float hi) {  // {bf16(lo), bf16(hi)}
    u32 r;
    asm("v_cvt_pk_bf16_f32 %0, %1, %2" : "=v"(r) : "v"(lo), "v"(hi));
    return r;
}

// ---------------------------------------------------------------------------
// prep: blocks [0,512) convert wq/wk/wv [512][258] fp32 -> wb [1536][256] bf16
//       blocks [512,1536) transpose x [b][256][1024] fp32 -> xT [b][1024][256]
// ---------------------------------------------------------------------------
__global__ __launch_bounds__(256) void prep(
    const float* __restrict__ wq, const float* __restrict__ wk,
    const float* __restrict__ wv, const float* __restrict__ x,
    u16* __restrict__ wb, u16* __restrict__ xT)
{
    __shared__ float Lt[64][65];
    const int bid = blockIdx.x;
    const int tid = threadIdx.x;
    if (bid < 512) {
        int i = bid * 256 + tid;
        int o = i >> 8, c = i & 255;
        size_t si = (size_t)o * 258 + c;
        wb[i]          = f2bf(wq[si]);
        wb[131072 + i] = f2bf(wk[si]);
        wb[262144 + i] = f2bf(wv[si]);
    } else {
        int r = bid - 512;
        int n0 = (r & 15) * 64, c0 = ((r >> 4) & 3) * 64, b = r >> 6;
#pragma unroll
        for (int p = 0; p < 4; ++p) {
            int c = p * 16 + (tid >> 4);
            int nn = (tid & 15) * 4;
            float4 v = *(const float4*)&x[((size_t)(b * 256) + c0 + c) * 1024 + n0 + nn];
            Lt[c][nn + 0] = v.x; Lt[c][nn + 1] = v.y;
            Lt[c][nn + 2] = v.z; Lt[c][nn + 3] = v.w;
        }
        __syncthreads();
#pragma unroll
        for (int p = 0; p < 4; ++p) {
            int n = p * 16 + (tid >> 4);
            int cc = (tid & 15) * 4;
            ushort4 st;
            st.x = f2bf(Lt[cc + 0][n]); st.y = f2bf(Lt[cc + 1][n]);
            st.z = f2bf(Lt[cc + 2][n]); st.w = f2bf(Lt[cc + 3][n]);
            *(ushort4*)&xT[((size_t)(b << 10) + n0 + n) * 256 + c0 + cc] = st;
        }
    }
}

// ---------------------------------------------------------------------------
// Fused QKV GEMM, 128x128 tile, BK=64. Grid (8 nt, 12 mt, 16 b).
// mt covers 128 rows of the combined [1536][256] weight: mat = mt>>2.
// mat 0=Q token-major [bh][n][64]; mat 1=K (pre-scaled 0.125*log2e) token-
// major; mat 2=V d-major [bh][64][n]. Linear [128][64] LDS tiles with the
// attn-proven XOR swizzle (col8 ^ (row&7)<<3) on staging AND reads.
// ---------------------------------------------------------------------------
__global__ __launch_bounds__(256) void qkv_mfma(
    const u16* __restrict__ xT, const u16* __restrict__ wb,
    const float* __restrict__ wq, const float* __restrict__ wk,
    const float* __restrict__ wv,
    const float* __restrict__ bq, const float* __restrict__ bk,
    const float* __restrict__ bv,
    u16* __restrict__ qkvbuf)
{
    __shared__ u16 Wl[128 * 64];   // elem(r,c) at r*64 + (c ^ ((r&7)<<3))
    __shared__ u16 Tl[128 * 64];
    const int tid = threadIdx.x;
    const int lane = tid & 63, w = tid >> 6;
    const int quad = lane >> 4, m15 = lane & 15;
    const int n0 = blockIdx.x * 128, mt = blockIdx.y, b = blockIdx.z;
    const int mat = mt >> 2;
    const int m0 = mt * 128;                    // row in combined W
    const float* worig = (mat == 0) ? wq : ((mat == 1) ? wk : wv);
    const float* bias  = (mat == 0) ? bq : ((mat == 1) ? bk : bv);
    const float oscale = (mat == 1) ? 0.1803368801111204f : 1.0f;  // 0.125*log2(e)
    u16* outbuf = qkvbuf + (size_t)mat * 8388608;

    float4_ acc[2][8];
#pragma unroll
    for (int s = 0; s < 2; ++s)
#pragma unroll
        for (int t = 0; t < 8; ++t) acc[s][t] = (float4_){0, 0, 0, 0};

    const int row = tid >> 3, c8 = (tid & 7) * 8;     // 32 rows x 64 cols per pass
    const int stsw = c8 ^ ((row & 7) << 3);           // staging col swizzle
    const int rdsw = (m15 & 7) << 3;                  // fragment-read col XOR

    for (int cc0 = 0; cc0 < 256; cc0 += 64) {
        __syncthreads();
#pragma unroll
        for (int rr = 0; rr < 128; rr += 32) {
            *(short8*)&Wl[(row + rr) * 64 + stsw] =
                *(const short8*)(wb + (size_t)(m0 + row + rr) * 256 + cc0 + c8);
            *(short8*)&Tl[(row + rr) * 64 + stsw] =
                *(const short8*)(xT + ((size_t)(b << 10) + n0 + row + rr) * 256 + cc0 + c8);
        }
        __syncthreads();
#pragma unroll
        for (int c = 0; c < 2; ++c) {
            short8 af[2];
#pragma unroll
            for (int s = 0; s < 2; ++s)
                af[s] = *(const short8*)&Wl[(w * 32 + s * 16 + m15) * 64 +
                                            ((c * 32 + quad * 8) ^ rdsw)];
#pragma unroll
            for (int t = 0; t < 8; ++t) {
                short8 bf = *(const short8*)&Tl[(t * 16 + m15) * 64 +
                                                ((c * 32 + quad * 8) ^ rdsw)];
#pragma unroll
                for (int s = 0; s < 2; ++s)
                    acc[s][t] = MFMA16(af[s], bf, acc[s][t]);
            }
        }
    }

    // epilogue: rank-2 pos + bias, scale, store. om = row within this mat's 512.
#pragma unroll
    for (int s = 0; s < 2; ++s) {
        float wg[4], wx[4], bi[4];
#pragma unroll
        for (int r = 0; r < 4; ++r) {
            int om = (mt & 3) * 128 + w * 32 + s * 16 + quad * 4 + r;
            wg[r] = worig[(size_t)om * 258 + 256];
            wx[r] = worig[(size_t)om * 258 + 257];
            bi[r] = bias[om];
        }
        const int h = (mt & 3) * 2 + ((w * 32 + s * 16) >> 6);
        const int dbase = ((w * 32 + s * 16) & 63) + quad * 4;
#pragma unroll
        for (int t = 0; t < 8; ++t) {
            int n = n0 + t * 16 + m15;
            float gy = -1.0f + 2.0f * (float)(n >> 5) / 31.0f;
            float gx = -1.0f + 2.0f * (float)(n & 31) / 31.0f;
            float v[4];
#pragma unroll
            for (int r = 0; r < 4; ++r)
                v[r] = (acc[s][t][r] + wg[r] * gy + wx[r] * gx + bi[r]) * oscale;
            if (mat != 2) {      // token-major [bh][n][64]
                ushort4 st;
                st.x = f2bf(v[0]); st.y = f2bf(v[1]);
                st.z = f2bf(v[2]); st.w = f2bf(v[3]);
                *(ushort4*)&outbuf[((size_t)(b * 8 + h) * 1024 + n) * 64 + dbase] = st;
            } else {             // d-major [bh][64][n]
#pragma unroll
                for (int r = 0; r < 4; ++r)
                    outbuf[((size_t)(b * 8 + h) * 64 + dbase + r) * 1024 + n] = f2bf(v[r]);
            }
        }
    }
}

// ---------------------------------------------------------------------------
// Attention (round 16, unchanged): block = (bh, q-tile 128), 8 waves x 16
// q-rows, 512 threads. Swapped QK^T; exp2 softmax; conflict-free Pl cells.
// Output in-place over qbuf [bh][n][64]. Grid (128 bh, 8 qt).
// ---------------------------------------------------------------------------
__global__ __launch_bounds__(512) void attn_mfma(
    u16* __restrict__ qbuf, const u16* __restrict__ kbuf,
    const u16* __restrict__ vbuf)
{
    __shared__ u16 Kl[64 * 64];      // [kt][d], elem(kt,d) at kt*64 + (d ^ ((kt&7)<<3))
    __shared__ u16 Vl[64 * 64];      // V^T [d][kt], elem(d,kt) at d*64 + (kt ^ ((d&7)<<3))
    __shared__ u16 Pl[8][8][16][8];  // per-wave P^T cells: [w][pair][col=q'][8 kt]

    const int tid = threadIdx.x;
    const int lane = tid & 63, w = tid >> 6;          // w in [0,8)
    const int quad = lane >> 4, m15 = lane & 15;
    const int bh = blockIdx.x;
    const int q0 = blockIdx.y * 128;
    u16* qb = qbuf + (size_t)bh * 65536;
    const u16* kb = kbuf + (size_t)bh * 65536;   // [1024 n][64 d]
    const u16* vb = vbuf + (size_t)bh * 65536;   // [64 d][1024 n]

    // Q frags (B-operand): wave w owns q rows q0 + w*16 + [0,16)
    short8 qf[2];
    {
        const u16* qr = qb + (size_t)(q0 + w * 16 + m15) * 64 + quad * 8;
        qf[0] = *(const short8*)qr;
        qf[1] = *(const short8*)(qr + 32);
    }

    float4_ O[4];                    // O^T tiles
    float lp = 0.0f;                 // per-lane partial l
#pragma unroll
    for (int t = 0; t < 4; ++t) O[t] = (float4_){0, 0, 0, 0};

    const int row = tid >> 3, c8 = (tid & 7) * 8;     // 512 thr cover 64 rows x 64 cols
    const int stsw = c8 ^ ((row & 7) << 3);           // K/V staging col swizzle (u16)
    const int rdsw = (m15 & 7) << 3;                  // K/V fragment-read col XOR (u16)

    for (int kt0 = 0; kt0 < 1024; kt0 += 64) {
        __syncthreads();
        *(short8*)&Kl[row * 64 + stsw] =
            *(const short8*)(kb + (size_t)(kt0 + row) * 64 + c8);
        *(short8*)&Vl[row * 64 + stsw] =
            *(const short8*)(vb + (size_t)row * 1024 + kt0 + c8);
        __syncthreads();

        // GEMM1 (swapped): lane holds S^T[kt=t*16+quad*4+r][q'=m15]
        float4_ S[4];
#pragma unroll
        for (int t = 0; t < 4; ++t) S[t] = (float4_){0, 0, 0, 0};
#pragma unroll
        for (int c = 0; c < 2; ++c) {
            short8 kf[4];
#pragma unroll
            for (int t = 0; t < 4; ++t)
                kf[t] = *(const short8*)&Kl[(t * 16 + m15) * 64 +
                                            ((c * 32 + quad * 8) ^ rdsw)];
            __builtin_amdgcn_s_setprio(1);
#pragma unroll
            for (int t = 0; t < 4; ++t)
                S[t] = MFMA16(kf[t], qf[c], S[t]);
            __builtin_amdgcn_s_setprio(0);
        }

        // exp2 + pack (cvt_pk) + b64 cell store; l partial
        {
            float lsum = 0.0f;
#pragma unroll
            for (int t = 0; t < 4; ++t) {
                float p0 = exp2_fast(S[t][0]);
                float p1 = exp2_fast(S[t][1]);
                float p2 = exp2_fast(S[t][2]);
                float p3 = exp2_fast(S[t][3]);
                uint2 st; st.x = cvtpk_bf16(p0, p1); st.y = cvtpk_bf16(p2, p3);
                // cell(pair = t*2 + (quad>>1), col = m15), half = quad&1
                *(uint2*)&Pl[w][t * 2 + (quad >> 1)][m15][(quad & 1) * 4] = st;
                lsum += (p0 + p1) + (p2 + p3);
            }
            lp += lsum;
        }

        // GEMM2: O^T[d][q'] += V^T[d][kt] * P^T[kt][q']
#pragma unroll
        for (int c = 0; c < 2; ++c) {
            short8 av[4];
#pragma unroll
            for (int dt = 0; dt < 4; ++dt)
                av[dt] = *(const short8*)&Vl[(dt * 16 + m15) * 64 +
                                             ((c * 32 + quad * 8) ^ rdsw)];
            short8 bp = *(const short8*)&Pl[w][c * 4 + quad][m15][0];
            __builtin_amdgcn_s_setprio(1);
#pragma unroll
            for (int dt = 0; dt < 4; ++dt)
                O[dt] = MFMA16(av[dt], bp, O[dt]);
            __builtin_amdgcn_s_setprio(0);
        }
    }

    // l: sum the 4 quad partials for column q'=m15 (all lanes end with full l)
    {
        float v = lp;
        v += __shfl_xor(v, 16);
        v += __shfl_xor(v, 32);
        float linv = 1.0f / v;
        int n = q0 + w * 16 + m15;
#pragma unroll
        for (int dt = 0; dt < 4; ++dt) {
            ushort4 st;
            st.x = f2bf(O[dt][0] * linv);
            st.y = f2bf(O[dt][1] * linv);
            st.z = f2bf(O[dt][2] * linv);
            st.w = f2bf(O[dt][3] * linv);
            // in-place over qbuf: [bh][n][64]
            *(ushort4*)&qb[(size_t)n * 64 + dt * 16 + quad * 4] = st;
        }
    }
}

// ---------------------------------------------------------------------------
// Output projection + bias + residual. AO read from qbuf [bh][n][64].
// Grid (16 nt, 4 ft, 16 b). Linear [64][64] tiles + attn-proven XOR swizzle;
// wo conversion via v_cvt_pk_bf16_f32.
// ---------------------------------------------------------------------------
__global__ __launch_bounds__(256) void proj_mfma(
    const u16* __restrict__ ao, const float* __restrict__ wo,
    const float* __restrict__ bo, const float* __restrict__ x,
    float* __restrict__ out)
{
    __shared__ u16 Wl[64 * 64];    // elem(r,c) at r*64 + (c ^ ((r&7)<<3))
    __shared__ u16 Tl[64 * 64];
    const int tid = threadIdx.x;
    const int lane = tid & 63, w = tid >> 6;
    const int quad = lane >> 4, m15 = lane & 15;
    const int n0 = blockIdx.x * 64, f0 = blockIdx.y * 64, b = blockIdx.z;

    float4_ acc[4] = {{0,0,0,0},{0,0,0,0},{0,0,0,0},{0,0,0,0}};
    const int row = tid >> 3, c8 = (tid & 7) * 8;
    const int stsw = c8 ^ ((row & 7) << 3);
    const int rdsw = (m15 & 7) << 3;

    for (int cc0 = 0; cc0 < 512; cc0 += 64) {
        __syncthreads();
        const int h = cc0 >> 6;
#pragma unroll
        for (int rr = 0; rr < 64; rr += 32) {
            const float* wsrc = wo + (size_t)(f0 + row + rr) * 512 + cc0 + c8;
            float4 v0 = *(const float4*)wsrc;
            float4 v1 = *(const float4*)(wsrc + 4);
            uint4 pk;
            pk.x = cvtpk_bf16(v0.x, v0.y);
            pk.y = cvtpk_bf16(v0.z, v0.w);
            pk.z = cvtpk_bf16(v1.x, v1.y);
            pk.w = cvtpk_bf16(v1.z, v1.w);
            *(uint4*)&Wl[(row + rr) * 64 + stsw] = pk;
            *(short8*)&Tl[(row + rr) * 64 + stsw] =
                *(const short8*)(ao + ((size_t)((b << 3) + h) * 1024 + n0 + row + rr) * 64 + c8);
        }
        __syncthreads();
#pragma unroll
        for (int c = 0; c < 2; ++c) {
            short8 af = *(const short8*)&Wl[(w * 16 + m15) * 64 +
                                            ((c * 32 + quad * 8) ^ rdsw)];
#pragma unroll
            for (int t = 0; t < 4; ++t) {
                short8 bf = *(const short8*)&Tl[(t * 16 + m15) * 64 +
                                                ((c * 32 + quad * 8) ^ rdsw)];
                acc[t] = MFMA16(af, bf, acc[t]);
            }
        }
    }

    float bi[4];
#pragma unroll
    for (int r = 0; r < 4; ++r) bi[r] = bo[f0 + w * 16 + quad * 4 + r];
#pragma unroll
    for (int t = 0; t < 4; ++t) {
        int n = n0 + t * 16 + m15;
#pragma unroll
        for (int r = 0; r < 4; ++r) {
            int f = f0 + w * 16 + quad * 4 + r;
            size_t idx = ((size_t)(b * 256) + f) * 1024 + n;
            out[idx] = acc[t][r] + bi[r] + x[idx];
        }
    }
}

extern "C" void kernel_launch(void* const* d_in, const int* in_sizes, int n_in,
                              void* d_out, int out_size, void* d_ws, size_t ws_size,
                              hipStream_t stream) {
    const float* x  = (const float*)d_in[0];
    const float* wq = (const float*)d_in[1];
    const float* bq = (const float*)d_in[2];
    const float* wk = (const float*)d_in[3];
    const float* bk = (const float*)d_in[4];
    const float* wv = (const float*)d_in[5];
    const float* bv = (const float*)d_in[6];
    const float* wo = (const float*)d_in[7];
    const float* bo = (const float*)d_in[8];

    // ws layout (u16 elems), ~59.8 MiB used:
    //   qkvbuf: 3 x 8,388,608 (Q, K, V). attn writes AO in-place over Q.
    //   region: xT[4,194,304] + wb[393,216] — no aliasing with anything live.
    u16* qkvbuf = (u16*)d_ws;
    u16* region = qkvbuf + 3 * 8388608;
    u16* xT = region;
    u16* wb = region + 4194304;

    prep<<<1536, 256, 0, stream>>>(wq, wk, wv, x, wb, xT);

    qkv_mfma<<<dim3(8, 12, 16), 256, 0, stream>>>(
        xT, wb, wq, wk, wv, bq, bk, bv, qkvbuf);

    attn_mfma<<<dim3(128, 8), 512, 0, stream>>>(
        qkvbuf, qkvbuf + 8388608, qkvbuf + 16777216);

    proj_mfma<<<dim3(16, 4, 16), 256, 0, stream>>>(qkvbuf, wo, bo, x, (float*)d_out);
}

// Round 11
// 186.404 us; speedup vs baseline: 1.0738x; 1.0074x over previous
//
#include <hip/hip_runtime.h>

// ResidualAttentionBlock (MFMA, round 18): B=16, FIN=256, H=W=32 (N=1024),
// NH=8, FH=64, CIN=258, COUT=512. Inputs fp32. v_mfma_f32_16x16x32_bf16,
// fp32 accumulation.
//
// Round 18 (attn only; prep/qkv/proj = round 17):
//  - attn reg-prefetch (T14), done right this time: round-8's spill was the
//    forced __launch_bounds__(256,4) VGPR=64 pin over a heavy 2-sub wave.
//    Round-16 wave is VGPR=36 with no forced bound; prefetching one K + one
//    V short8 adds exactly 8 VGPRs (~44-48 total, under the 64 cliff for
//    4x512thr blocks/CU). Loads issue at iter top; vmcnt wait lands at the
//    post-GEMM2 ds_write -> ~300-500cy staging latency hides under compute.
//  - Everything else identical to round 17 (best: 187.8us, attn 56.1us).

typedef unsigned short u16;
typedef unsigned int   u32;
typedef __attribute__((ext_vector_type(8))) short  short8;
typedef __attribute__((ext_vector_type(4))) float  float4_;

#define MFMA16(a, b, c) __builtin_amdgcn_mfma_f32_16x16x32_bf16(a, b, c, 0, 0, 0)

__device__ __forceinline__ float bf2f(u16 u) {
    union { u32 i; float f; } v; v.i = ((u32)u) << 16; return v.f;
}
__device__ __forceinline__ u16 f2bf(float f) {           // RNE
    union { float f; u32 i; } v; v.f = f;
    u32 r = v.i + 0x7FFFu + ((v.i >> 16) & 1u);
    return (u16)(r >> 16);
}
__device__ __forceinline__ float exp2_fast(float x) {    // 2^x
    float r;
    asm("v_exp_f32 %0, %1" : "=v"(r) : "v"(x));
    return r;
}
__device__ __forceinline__ u32 cvtpk_bf16(float lo, float hi) {  // {bf16(lo), bf16(hi)}
    u32 r;
    asm("v_cvt_pk_bf16_f32 %0, %1, %2" : "=v"(r) : "v"(lo), "v"(hi));
    return r;
}

// ---------------------------------------------------------------------------
// prep: blocks [0,512) convert wq/wk/wv [512][258] fp32 -> wb [1536][256] bf16
//       blocks [512,1536) transpose x [b][256][1024] fp32 -> xT [b][1024][256]
// ---------------------------------------------------------------------------
__global__ __launch_bounds__(256) void prep(
    const float* __restrict__ wq, const float* __restrict__ wk,
    const float* __restrict__ wv, const float* __restrict__ x,
    u16* __restrict__ wb, u16* __restrict__ xT)
{
    __shared__ float Lt[64][65];
    const int bid = blockIdx.x;
    const int tid = threadIdx.x;
    if (bid < 512) {
        int i = bid * 256 + tid;
        int o = i >> 8, c = i & 255;
        size_t si = (size_t)o * 258 + c;
        wb[i]          = f2bf(wq[si]);
        wb[131072 + i] = f2bf(wk[si]);
        wb[262144 + i] = f2bf(wv[si]);
    } else {
        int r = bid - 512;
        int n0 = (r & 15) * 64, c0 = ((r >> 4) & 3) * 64, b = r >> 6;
#pragma unroll
        for (int p = 0; p < 4; ++p) {
            int c = p * 16 + (tid >> 4);
            int nn = (tid & 15) * 4;
            float4 v = *(const float4*)&x[((size_t)(b * 256) + c0 + c) * 1024 + n0 + nn];
            Lt[c][nn + 0] = v.x; Lt[c][nn + 1] = v.y;
            Lt[c][nn + 2] = v.z; Lt[c][nn + 3] = v.w;
        }
        __syncthreads();
#pragma unroll
        for (int p = 0; p < 4; ++p) {
            int n = p * 16 + (tid >> 4);
            int cc = (tid & 15) * 4;
            ushort4 st;
            st.x = f2bf(Lt[cc + 0][n]); st.y = f2bf(Lt[cc + 1][n]);
            st.z = f2bf(Lt[cc + 2][n]); st.w = f2bf(Lt[cc + 3][n]);
            *(ushort4*)&xT[((size_t)(b << 10) + n0 + n) * 256 + c0 + cc] = st;
        }
    }
}

// ---------------------------------------------------------------------------
// Fused QKV GEMM, 128x128 tile, BK=64. Grid (8 nt, 12 mt, 16 b).
// mt covers 128 rows of the combined [1536][256] weight: mat = mt>>2.
// mat 0=Q token-major [bh][n][64]; mat 1=K (pre-scaled 0.125*log2e) token-
// major; mat 2=V d-major [bh][64][n]. Linear [128][64] LDS tiles with the
// attn-proven XOR swizzle (col8 ^ (row&7)<<3) on staging AND reads.
// ---------------------------------------------------------------------------
__global__ __launch_bounds__(256) void qkv_mfma(
    const u16* __restrict__ xT, const u16* __restrict__ wb,
    const float* __restrict__ wq, const float* __restrict__ wk,
    const float* __restrict__ wv,
    const float* __restrict__ bq, const float* __restrict__ bk,
    const float* __restrict__ bv,
    u16* __restrict__ qkvbuf)
{
    __shared__ u16 Wl[128 * 64];   // elem(r,c) at r*64 + (c ^ ((r&7)<<3))
    __shared__ u16 Tl[128 * 64];
    const int tid = threadIdx.x;
    const int lane = tid & 63, w = tid >> 6;
    const int quad = lane >> 4, m15 = lane & 15;
    const int n0 = blockIdx.x * 128, mt = blockIdx.y, b = blockIdx.z;
    const int mat = mt >> 2;
    const int m0 = mt * 128;                    // row in combined W
    const float* worig = (mat == 0) ? wq : ((mat == 1) ? wk : wv);
    const float* bias  = (mat == 0) ? bq : ((mat == 1) ? bk : bv);
    const float oscale = (mat == 1) ? 0.1803368801111204f : 1.0f;  // 0.125*log2(e)
    u16* outbuf = qkvbuf + (size_t)mat * 8388608;

    float4_ acc[2][8];
#pragma unroll
    for (int s = 0; s < 2; ++s)
#pragma unroll
        for (int t = 0; t < 8; ++t) acc[s][t] = (float4_){0, 0, 0, 0};

    const int row = tid >> 3, c8 = (tid & 7) * 8;     // 32 rows x 64 cols per pass
    const int stsw = c8 ^ ((row & 7) << 3);           // staging col swizzle
    const int rdsw = (m15 & 7) << 3;                  // fragment-read col XOR

    for (int cc0 = 0; cc0 < 256; cc0 += 64) {
        __syncthreads();
#pragma unroll
        for (int rr = 0; rr < 128; rr += 32) {
            *(short8*)&Wl[(row + rr) * 64 + stsw] =
                *(const short8*)(wb + (size_t)(m0 + row + rr) * 256 + cc0 + c8);
            *(short8*)&Tl[(row + rr) * 64 + stsw] =
                *(const short8*)(xT + ((size_t)(b << 10) + n0 + row + rr) * 256 + cc0 + c8);
        }
        __syncthreads();
#pragma unroll
        for (int c = 0; c < 2; ++c) {
            short8 af[2];
#pragma unroll
            for (int s = 0; s < 2; ++s)
                af[s] = *(const short8*)&Wl[(w * 32 + s * 16 + m15) * 64 +
                                            ((c * 32 + quad * 8) ^ rdsw)];
#pragma unroll
            for (int t = 0; t < 8; ++t) {
                short8 bf = *(const short8*)&Tl[(t * 16 + m15) * 64 +
                                                ((c * 32 + quad * 8) ^ rdsw)];
#pragma unroll
                for (int s = 0; s < 2; ++s)
                    acc[s][t] = MFMA16(af[s], bf, acc[s][t]);
            }
        }
    }

    // epilogue: rank-2 pos + bias, scale, store. om = row within this mat's 512.
#pragma unroll
    for (int s = 0; s < 2; ++s) {
        float wg[4], wx[4], bi[4];
#pragma unroll
        for (int r = 0; r < 4; ++r) {
            int om = (mt & 3) * 128 + w * 32 + s * 16 + quad * 4 + r;
            wg[r] = worig[(size_t)om * 258 + 256];
            wx[r] = worig[(size_t)om * 258 + 257];
            bi[r] = bias[om];
        }
        const int h = (mt & 3) * 2 + ((w * 32 + s * 16) >> 6);
        const int dbase = ((w * 32 + s * 16) & 63) + quad * 4;
#pragma unroll
        for (int t = 0; t < 8; ++t) {
            int n = n0 + t * 16 + m15;
            float gy = -1.0f + 2.0f * (float)(n >> 5) / 31.0f;
            float gx = -1.0f + 2.0f * (float)(n & 31) / 31.0f;
            float v[4];
#pragma unroll
            for (int r = 0; r < 4; ++r)
                v[r] = (acc[s][t][r] + wg[r] * gy + wx[r] * gx + bi[r]) * oscale;
            if (mat != 2) {      // token-major [bh][n][64]
                ushort4 st;
                st.x = f2bf(v[0]); st.y = f2bf(v[1]);
                st.z = f2bf(v[2]); st.w = f2bf(v[3]);
                *(ushort4*)&outbuf[((size_t)(b * 8 + h) * 1024 + n) * 64 + dbase] = st;
            } else {             // d-major [bh][64][n]
#pragma unroll
                for (int r = 0; r < 4; ++r)
                    outbuf[((size_t)(b * 8 + h) * 64 + dbase + r) * 1024 + n] = f2bf(v[r]);
            }
        }
    }
}

// ---------------------------------------------------------------------------
// Attention (round 18): round-16 structure + register K/V prefetch.
// block = (bh, q-tile 128), 8 waves x 16 q-rows, 512 threads. Swapped QK^T;
// exp2 softmax; conflict-free Pl cells. Output in-place over qbuf [bh][n][64].
// Grid (128 bh, 8 qt). LDS 32.8KB -> 4 blocks/CU.
// ---------------------------------------------------------------------------
__global__ __launch_bounds__(512) void attn_mfma(
    u16* __restrict__ qbuf, const u16* __restrict__ kbuf,
    const u16* __restrict__ vbuf)
{
    __shared__ u16 Kl[64 * 64];      // [kt][d], elem(kt,d) at kt*64 + (d ^ ((kt&7)<<3))
    __shared__ u16 Vl[64 * 64];      // V^T [d][kt], elem(d,kt) at d*64 + (kt ^ ((d&7)<<3))
    __shared__ u16 Pl[8][8][16][8];  // per-wave P^T cells: [w][pair][col=q'][8 kt]

    const int tid = threadIdx.x;
    const int lane = tid & 63, w = tid >> 6;          // w in [0,8)
    const int quad = lane >> 4, m15 = lane & 15;
    const int bh = blockIdx.x;
    const int q0 = blockIdx.y * 128;
    u16* qb = qbuf + (size_t)bh * 65536;
    const u16* kb = kbuf + (size_t)bh * 65536;   // [1024 n][64 d]
    const u16* vb = vbuf + (size_t)bh * 65536;   // [64 d][1024 n]

    // Q frags (B-operand): wave w owns q rows q0 + w*16 + [0,16)
    short8 qf[2];
    {
        const u16* qr = qb + (size_t)(q0 + w * 16 + m15) * 64 + quad * 8;
        qf[0] = *(const short8*)qr;
        qf[1] = *(const short8*)(qr + 32);
    }

    float4_ O[4];                    // O^T tiles
    float lp = 0.0f;                 // per-lane partial l
#pragma unroll
    for (int t = 0; t < 4; ++t) O[t] = (float4_){0, 0, 0, 0};

    const int row = tid >> 3, c8 = (tid & 7) * 8;     // 512 thr cover 64 rows x 64 cols
    const int stsw = c8 ^ ((row & 7) << 3);           // K/V staging col swizzle (u16)
    const int rdsw = (m15 & 7) << 3;                  // K/V fragment-read col XOR (u16)

    // prologue: stage tile 0 directly
    {
        short8 k0 = *(const short8*)(kb + (size_t)row * 64 + c8);
        short8 v0 = *(const short8*)(vb + (size_t)row * 1024 + c8);
        *(short8*)&Kl[row * 64 + stsw] = k0;
        *(short8*)&Vl[row * 64 + stsw] = v0;
    }
    __syncthreads();

    short8 kr, vr;                   // prefetch registers (8 VGPRs)
    for (int kt0 = 0; kt0 < 1024; kt0 += 64) {
        const bool more = (kt0 < 960);
        if (more) {                  // issue next-tile loads; wait lands at ds_write
            kr = *(const short8*)(kb + (size_t)(kt0 + 64 + row) * 64 + c8);
            vr = *(const short8*)(vb + (size_t)row * 1024 + kt0 + 64 + c8);
        }

        // GEMM1 (swapped): lane holds S^T[kt=t*16+quad*4+r][q'=m15]
        float4_ S[4];
#pragma unroll
        for (int t = 0; t < 4; ++t) S[t] = (float4_){0, 0, 0, 0};
#pragma unroll
        for (int c = 0; c < 2; ++c) {
            short8 kf[4];
#pragma unroll
            for (int t = 0; t < 4; ++t)
                kf[t] = *(const short8*)&Kl[(t * 16 + m15) * 64 +
                                            ((c * 32 + quad * 8) ^ rdsw)];
            __builtin_amdgcn_s_setprio(1);
#pragma unroll
            for (int t = 0; t < 4; ++t)
                S[t] = MFMA16(kf[t], qf[c], S[t]);
            __builtin_amdgcn_s_setprio(0);
        }

        // exp2 + pack (cvt_pk) + b64 cell store; l partial
        {
            float lsum = 0.0f;
#pragma unroll
            for (int t = 0; t < 4; ++t) {
                float p0 = exp2_fast(S[t][0]);
                float p1 = exp2_fast(S[t][1]);
                float p2 = exp2_fast(S[t][2]);
                float p3 = exp2_fast(S[t][3]);
                uint2 st; st.x = cvtpk_bf16(p0, p1); st.y = cvtpk_bf16(p2, p3);
                // cell(pair = t*2 + (quad>>1), col = m15), half = quad&1
                *(uint2*)&Pl[w][t * 2 + (quad >> 1)][m15][(quad & 1) * 4] = st;
                lsum += (p0 + p1) + (p2 + p3);
            }
            lp += lsum;
        }

        // GEMM2: O^T[d][q'] += V^T[d][kt] * P^T[kt][q']
#pragma unroll
        for (int c = 0; c < 2; ++c) {
            short8 av[4];
#pragma unroll
            for (int dt = 0; dt < 4; ++dt)
                av[dt] = *(const short8*)&Vl[(dt * 16 + m15) * 64 +
                                             ((c * 32 + quad * 8) ^ rdsw)];
            short8 bp = *(const short8*)&Pl[w][c * 4 + quad][m15][0];
            __builtin_amdgcn_s_setprio(1);
#pragma unroll
            for (int dt = 0; dt < 4; ++dt)
                O[dt] = MFMA16(av[dt], bp, O[dt]);
            __builtin_amdgcn_s_setprio(0);
        }

        __syncthreads();             // all waves done reading Kl/Vl
        if (more) {                  // write prefetched tile (vmcnt wait here)
            *(short8*)&Kl[row * 64 + stsw] = kr;
            *(short8*)&Vl[row * 64 + stsw] = vr;
            __syncthreads();
        }
    }

    // l: sum the 4 quad partials for column q'=m15 (all lanes end with full l)
    {
        float v = lp;
        v += __shfl_xor(v, 16);
        v += __shfl_xor(v, 32);
        float linv = 1.0f / v;
        int n = q0 + w * 16 + m15;
#pragma unroll
        for (int dt = 0; dt < 4; ++dt) {
            ushort4 st;
            st.x = f2bf(O[dt][0] * linv);
            st.y = f2bf(O[dt][1] * linv);
            st.z = f2bf(O[dt][2] * linv);
            st.w = f2bf(O[dt][3] * linv);
            // in-place over qbuf: [bh][n][64]
            *(ushort4*)&qb[(size_t)n * 64 + dt * 16 + quad * 4] = st;
        }
    }
}

// ---------------------------------------------------------------------------
// Output projection + bias + residual. AO read from qbuf [bh][n][64].
// Grid (16 nt, 4 ft, 16 b). Linear [64][64] tiles + attn-proven XOR swizzle;
// wo conversion via v_cvt_pk_bf16_f32.
// ---------------------------------------------------------------------------
__global__ __launch_bounds__(256) void proj_mfma(
    const u16* __restrict__ ao, const float* __restrict__ wo,
    const float* __restrict__ bo, const float* __restrict__ x,
    float* __restrict__ out)
{
    __shared__ u16 Wl[64 * 64];    // elem(r,c) at r*64 + (c ^ ((r&7)<<3))
    __shared__ u16 Tl[64 * 64];
    const int tid = threadIdx.x;
    const int lane = tid & 63, w = tid >> 6;
    const int quad = lane >> 4, m15 = lane & 15;
    const int n0 = blockIdx.x * 64, f0 = blockIdx.y * 64, b = blockIdx.z;

    float4_ acc[4] = {{0,0,0,0},{0,0,0,0},{0,0,0,0},{0,0,0,0}};
    const int row = tid >> 3, c8 = (tid & 7) * 8;
    const int stsw = c8 ^ ((row & 7) << 3);
    const int rdsw = (m15 & 7) << 3;

    for (int cc0 = 0; cc0 < 512; cc0 += 64) {
        __syncthreads();
        const int h = cc0 >> 6;
#pragma unroll
        for (int rr = 0; rr < 64; rr += 32) {
            const float* wsrc = wo + (size_t)(f0 + row + rr) * 512 + cc0 + c8;
            float4 v0 = *(const float4*)wsrc;
            float4 v1 = *(const float4*)(wsrc + 4);
            uint4 pk;
            pk.x = cvtpk_bf16(v0.x, v0.y);
            pk.y = cvtpk_bf16(v0.z, v0.w);
            pk.z = cvtpk_bf16(v1.x, v1.y);
            pk.w = cvtpk_bf16(v1.z, v1.w);
            *(uint4*)&Wl[(row + rr) * 64 + stsw] = pk;
            *(short8*)&Tl[(row + rr) * 64 + stsw] =
                *(const short8*)(ao + ((size_t)((b << 3) + h) * 1024 + n0 + row + rr) * 64 + c8);
        }
        __syncthreads();
#pragma unroll
        for (int c = 0; c < 2; ++c) {
            short8 af = *(const short8*)&Wl[(w * 16 + m15) * 64 +
                                            ((c * 32 + quad * 8) ^ rdsw)];
#pragma unroll
            for (int t = 0; t < 4; ++t) {
                short8 bf = *(const short8*)&Tl[(t * 16 + m15) * 64 +
                                                ((c * 32 + quad * 8) ^ rdsw)];
                acc[t] = MFMA16(af, bf, acc[t]);
            }
        }
    }

    float bi[4];
#pragma unroll
    for (int r = 0; r < 4; ++r) bi[r] = bo[f0 + w * 16 + quad * 4 + r];
#pragma unroll
    for (int t = 0; t < 4; ++t) {
        int n = n0 + t * 16 + m15;
#pragma unroll
        for (int r = 0; r < 4; ++r) {
            int f = f0 + w * 16 + quad * 4 + r;
            size_t idx = ((size_t)(b * 256) + f) * 1024 + n;
            out[idx] = acc[t][r] + bi[r] + x[idx];
        }
    }
}

extern "C" void kernel_launch(void* const* d_in, const int* in_sizes, int n_in,
                              void* d_out, int out_size, void* d_ws, size_t ws_size,
                              hipStream_t stream) {
    const float* x  = (const float*)d_in[0];
    const float* wq = (const float*)d_in[1];
    const float* bq = (const float*)d_in[2];
    const float* wk = (const float*)d_in[3];
    const float* bk = (const float*)d_in[4];
    const float* wv = (const float*)d_in[5];
    const float* bv = (const float*)d_in[6];
    const float* wo = (const float*)d_in[7];
    const float* bo = (const float*)d_in[8];

    // ws layout (u16 elems), ~59.8 MiB used:
    //   qkvbuf: 3 x 8,388,608 (Q, K, V). attn writes AO in-place over Q.
    //   region: xT[4,194,304] + wb[393,216] — no aliasing with anything live.
    u16* qkvbuf = (u16*)d_ws;
    u16* region = qkvbuf + 3 * 8388608;
    u16* xT = region;
    u16* wb = region + 4194304;

    prep<<<1536, 256, 0, stream>>>(wq, wk, wv, x, wb, xT);

    qkv_mfma<<<dim3(8, 12, 16), 256, 0, stream>>>(
        xT, wb, wq, wk, wv, bq, bk, bv, qkvbuf);

    attn_mfma<<<dim3(128, 8), 512, 0, stream>>>(
        qkvbuf, qkvbuf + 8388608, qkvbuf + 16777216);

    proj_mfma<<<dim3(16, 4, 16), 256, 0, stream>>>(qkvbuf, wo, bo, x, (float*)d_out);
}

// Round 12
// 174.287 us; speedup vs baseline: 1.1484x; 1.0695x over previous
//
#include <hip/hip_runtime.h>

// ResidualAttentionBlock (MFMA, round 19): B=16, FIN=256, H=W=32 (N=1024),
// NH=8, FH=64, CIN=258, COUT=512. Inputs fp32. v_mfma_f32_16x16x32_bf16,
// fp32 accumulation.
//
// Round 19 (qkv only; prep/attn/proj = round 18):
//  - Round-18: attn reg-prefetch worked (attn out of top-5). qkv now top:
//    62us, MfmaUtil 7.2%, conflicts 0, FETCH/WRITE ideal -> pure exposed
//    staging latency (8 global b128 serially between barriers, x4 iters).
//  - qkv K-step 64->32 as a software pipeline over the SAME [128][64] LDS:
//    the two 32-col logical K-parities are physically disjoint under the
//    per-row XOR swizzle (bijective), so buffer p^1 can be written while
//    other waves still compute on p. Per step: issue 4 global loads (regs)
//    -> 16 MFMA on p -> ds_write p^1 -> ONE barrier. Latency hides under
//    compute; VGPR ~88+32 stays in (64,128] band -> occupancy unchanged.
//  - Tripwire: WRITE_SIZE >> 53MB = spill.

typedef unsigned short u16;
typedef unsigned int   u32;
typedef __attribute__((ext_vector_type(8))) short  short8;
typedef __attribute__((ext_vector_type(4))) float  float4_;

#define MFMA16(a, b, c) __builtin_amdgcn_mfma_f32_16x16x32_bf16(a, b, c, 0, 0, 0)

__device__ __forceinline__ float bf2f(u16 u) {
    union { u32 i; float f; } v; v.i = ((u32)u) << 16; return v.f;
}
__device__ __forceinline__ u16 f2bf(float f) {           // RNE
    union { float f; u32 i; } v; v.f = f;
    u32 r = v.i + 0x7FFFu + ((v.i >> 16) & 1u);
    return (u16)(r >> 16);
}
__device__ __forceinline__ float exp2_fast(float x) {    // 2^x
    float r;
    asm("v_exp_f32 %0, %1" : "=v"(r) : "v"(x));
    return r;
}
__device__ __forceinline__ u32 cvtpk_bf16(float lo, float hi) {  // {bf16(lo), bf16(hi)}
    u32 r;
    asm("v_cvt_pk_bf16_f32 %0, %1, %2" : "=v"(r) : "v"(lo), "v"(hi));
    return r;
}

// ---------------------------------------------------------------------------
// prep: blocks [0,512) convert wq/wk/wv [512][258] fp32 -> wb [1536][256] bf16
//       blocks [512,1536) transpose x [b][256][1024] fp32 -> xT [b][1024][256]
// ---------------------------------------------------------------------------
__global__ __launch_bounds__(256) void prep(
    const float* __restrict__ wq, const float* __restrict__ wk,
    const float* __restrict__ wv, const float* __restrict__ x,
    u16* __restrict__ wb, u16* __restrict__ xT)
{
    __shared__ float Lt[64][65];
    const int bid = blockIdx.x;
    const int tid = threadIdx.x;
    if (bid < 512) {
        int i = bid * 256 + tid;
        int o = i >> 8, c = i & 255;
        size_t si = (size_t)o * 258 + c;
        wb[i]          = f2bf(wq[si]);
        wb[131072 + i] = f2bf(wk[si]);
        wb[262144 + i] = f2bf(wv[si]);
    } else {
        int r = bid - 512;
        int n0 = (r & 15) * 64, c0 = ((r >> 4) & 3) * 64, b = r >> 6;
#pragma unroll
        for (int p = 0; p < 4; ++p) {
            int c = p * 16 + (tid >> 4);
            int nn = (tid & 15) * 4;
            float4 v = *(const float4*)&x[((size_t)(b * 256) + c0 + c) * 1024 + n0 + nn];
            Lt[c][nn + 0] = v.x; Lt[c][nn + 1] = v.y;
            Lt[c][nn + 2] = v.z; Lt[c][nn + 3] = v.w;
        }
        __syncthreads();
#pragma unroll
        for (int p = 0; p < 4; ++p) {
            int n = p * 16 + (tid >> 4);
            int cc = (tid & 15) * 4;
            ushort4 st;
            st.x = f2bf(Lt[cc + 0][n]); st.y = f2bf(Lt[cc + 1][n]);
            st.z = f2bf(Lt[cc + 2][n]); st.w = f2bf(Lt[cc + 3][n]);
            *(ushort4*)&xT[((size_t)(b << 10) + n0 + n) * 256 + c0 + cc] = st;
        }
    }
}

// ---------------------------------------------------------------------------
// Fused QKV GEMM, 128x128 tile, software-pipelined K-step 32 over a [128][64]
// double-parity LDS. Grid (8 nt, 12 mt, 16 b). mat 0=Q token-major
// [bh][n][64]; mat 1=K (pre-scaled 0.125*log2e) token-major; mat 2=V d-major.
// ---------------------------------------------------------------------------
__global__ __launch_bounds__(256) void qkv_mfma(
    const u16* __restrict__ xT, const u16* __restrict__ wb,
    const float* __restrict__ wq, const float* __restrict__ wk,
    const float* __restrict__ wv,
    const float* __restrict__ bq, const float* __restrict__ bk,
    const float* __restrict__ bv,
    u16* __restrict__ qkvbuf)
{
    __shared__ u16 Wl[128 * 64];   // logical (row, lc): phys = row*64 + (lc ^ ((row&7)<<3))
    __shared__ u16 Tl[128 * 64];   // lc in [0,32) = parity 0, [32,64) = parity 1
    const int tid = threadIdx.x;
    const int lane = tid & 63, w = tid >> 6;
    const int quad = lane >> 4, m15 = lane & 15;
    const int n0 = blockIdx.x * 128, mt = blockIdx.y, b = blockIdx.z;
    const int mat = mt >> 2;
    const int m0 = mt * 128;                    // row in combined W
    const float* worig = (mat == 0) ? wq : ((mat == 1) ? wk : wv);
    const float* bias  = (mat == 0) ? bq : ((mat == 1) ? bk : bv);
    const float oscale = (mat == 1) ? 0.1803368801111204f : 1.0f;  // 0.125*log2(e)
    u16* outbuf = qkvbuf + (size_t)mat * 8388608;

    float4_ acc[2][8];
#pragma unroll
    for (int s = 0; s < 2; ++s)
#pragma unroll
        for (int t = 0; t < 8; ++t) acc[s][t] = (float4_){0, 0, 0, 0};

    // staging map: thread covers rows {srow, srow+64}, 8 cols at sc8, both arrays
    const int srow = tid >> 2;                 // 0..63
    const int sc8  = (tid & 3) * 8;            // 0,8,16,24 (within 32-col K-step)
    const int rdsw = (m15 & 7) << 3;           // fragment-read col XOR
    const int sw0  = (srow & 7) << 3;          // staging swizzle, rows srow / srow+64 (same &7)

    const u16* wsrc = wb + (size_t)(m0 + srow) * 256 + sc8;
    const u16* tsrc = xT + ((size_t)(b << 10) + n0 + srow) * 256 + sc8;

    // prologue: stage K-step 0 into parity 0
    {
        short8 w0 = *(const short8*)(wsrc);
        short8 w1 = *(const short8*)(wsrc + 64 * 256);
        short8 t0 = *(const short8*)(tsrc);
        short8 t1 = *(const short8*)(tsrc + 64 * 256);
        *(short8*)&Wl[srow * 64 + (sc8 ^ sw0)]        = w0;
        *(short8*)&Wl[(srow + 64) * 64 + (sc8 ^ sw0)] = w1;
        *(short8*)&Tl[srow * 64 + (sc8 ^ sw0)]        = t0;
        *(short8*)&Tl[(srow + 64) * 64 + (sc8 ^ sw0)] = t1;
    }
    __syncthreads();

#pragma unroll
    for (int k = 0; k < 8; ++k) {
        const int p = k & 1;
        short8 pw0, pw1, pt0, pt1;
        if (k < 7) {                           // issue next-step loads (regs)
            const int kc = (k + 1) * 32;
            pw0 = *(const short8*)(wsrc + kc);
            pw1 = *(const short8*)(wsrc + 64 * 256 + kc);
            pt0 = *(const short8*)(tsrc + kc);
            pt1 = *(const short8*)(tsrc + 64 * 256 + kc);
        }

        // compute step k on parity p (logical col base p*32 + quad*8)
        const int cb = p * 32 + quad * 8;
        short8 af0 = *(const short8*)&Wl[(w * 32 + m15) * 64 + (cb ^ rdsw)];
        short8 af1 = *(const short8*)&Wl[(w * 32 + 16 + m15) * 64 + (cb ^ rdsw)];
        __builtin_amdgcn_s_setprio(1);
#pragma unroll
        for (int t = 0; t < 8; ++t) {
            short8 bf = *(const short8*)&Tl[(t * 16 + m15) * 64 + (cb ^ rdsw)];
            acc[0][t] = MFMA16(af0, bf, acc[0][t]);
            acc[1][t] = MFMA16(af1, bf, acc[1][t]);
        }
        __builtin_amdgcn_s_setprio(0);

        if (k < 7) {                           // write parity p^1 (vmcnt wait here;
            const int pc = (p ^ 1) * 32 + sc8; //  other waves only read parity p)
            *(short8*)&Wl[srow * 64 + (pc ^ sw0)]        = pw0;
            *(short8*)&Wl[(srow + 64) * 64 + (pc ^ sw0)] = pw1;
            *(short8*)&Tl[srow * 64 + (pc ^ sw0)]        = pt0;
            *(short8*)&Tl[(srow + 64) * 64 + (pc ^ sw0)] = pt1;
        }
        __syncthreads();
    }

    // epilogue: rank-2 pos + bias, scale, store. om = row within this mat's 512.
#pragma unroll
    for (int s = 0; s < 2; ++s) {
        float wg[4], wx[4], bi[4];
#pragma unroll
        for (int r = 0; r < 4; ++r) {
            int om = (mt & 3) * 128 + w * 32 + s * 16 + quad * 4 + r;
            wg[r] = worig[(size_t)om * 258 + 256];
            wx[r] = worig[(size_t)om * 258 + 257];
            bi[r] = bias[om];
        }
        const int h = (mt & 3) * 2 + ((w * 32 + s * 16) >> 6);
        const int dbase = ((w * 32 + s * 16) & 63) + quad * 4;
#pragma unroll
        for (int t = 0; t < 8; ++t) {
            int n = n0 + t * 16 + m15;
            float gy = -1.0f + 2.0f * (float)(n >> 5) / 31.0f;
            float gx = -1.0f + 2.0f * (float)(n & 31) / 31.0f;
            float v[4];
#pragma unroll
            for (int r = 0; r < 4; ++r)
                v[r] = (acc[s][t][r] + wg[r] * gy + wx[r] * gx + bi[r]) * oscale;
            if (mat != 2) {      // token-major [bh][n][64]
                ushort4 st;
                st.x = f2bf(v[0]); st.y = f2bf(v[1]);
                st.z = f2bf(v[2]); st.w = f2bf(v[3]);
                *(ushort4*)&outbuf[((size_t)(b * 8 + h) * 1024 + n) * 64 + dbase] = st;
            } else {             // d-major [bh][64][n]
#pragma unroll
                for (int r = 0; r < 4; ++r)
                    outbuf[((size_t)(b * 8 + h) * 64 + dbase + r) * 1024 + n] = f2bf(v[r]);
            }
        }
    }
}

// ---------------------------------------------------------------------------
// Attention (round 18, unchanged): block = (bh, q-tile 128), 8 waves x 16
// q-rows, 512 threads, register K/V prefetch. Swapped QK^T; exp2 softmax;
// conflict-free Pl cells. Output in-place over qbuf [bh][n][64].
// Grid (128 bh, 8 qt). LDS 32.8KB -> 4 blocks/CU.
// ---------------------------------------------------------------------------
__global__ __launch_bounds__(512) void attn_mfma(
    u16* __restrict__ qbuf, const u16* __restrict__ kbuf,
    const u16* __restrict__ vbuf)
{
    __shared__ u16 Kl[64 * 64];      // [kt][d], elem(kt,d) at kt*64 + (d ^ ((kt&7)<<3))
    __shared__ u16 Vl[64 * 64];      // V^T [d][kt], elem(d,kt) at d*64 + (kt ^ ((d&7)<<3))
    __shared__ u16 Pl[8][8][16][8];  // per-wave P^T cells: [w][pair][col=q'][8 kt]

    const int tid = threadIdx.x;
    const int lane = tid & 63, w = tid >> 6;          // w in [0,8)
    const int quad = lane >> 4, m15 = lane & 15;
    const int bh = blockIdx.x;
    const int q0 = blockIdx.y * 128;
    u16* qb = qbuf + (size_t)bh * 65536;
    const u16* kb = kbuf + (size_t)bh * 65536;   // [1024 n][64 d]
    const u16* vb = vbuf + (size_t)bh * 65536;   // [64 d][1024 n]

    // Q frags (B-operand): wave w owns q rows q0 + w*16 + [0,16)
    short8 qf[2];
    {
        const u16* qr = qb + (size_t)(q0 + w * 16 + m15) * 64 + quad * 8;
        qf[0] = *(const short8*)qr;
        qf[1] = *(const short8*)(qr + 32);
    }

    float4_ O[4];                    // O^T tiles
    float lp = 0.0f;                 // per-lane partial l
#pragma unroll
    for (int t = 0; t < 4; ++t) O[t] = (float4_){0, 0, 0, 0};

    const int row = tid >> 3, c8 = (tid & 7) * 8;     // 512 thr cover 64 rows x 64 cols
    const int stsw = c8 ^ ((row & 7) << 3);           // K/V staging col swizzle (u16)
    const int rdsw = (m15 & 7) << 3;                  // K/V fragment-read col XOR (u16)

    // prologue: stage tile 0 directly
    {
        short8 k0 = *(const short8*)(kb + (size_t)row * 64 + c8);
        short8 v0 = *(const short8*)(vb + (size_t)row * 1024 + c8);
        *(short8*)&Kl[row * 64 + stsw] = k0;
        *(short8*)&Vl[row * 64 + stsw] = v0;
    }
    __syncthreads();

    short8 kr, vr;                   // prefetch registers (8 VGPRs)
    for (int kt0 = 0; kt0 < 1024; kt0 += 64) {
        const bool more = (kt0 < 960);
        if (more) {                  // issue next-tile loads; wait lands at ds_write
            kr = *(const short8*)(kb + (size_t)(kt0 + 64 + row) * 64 + c8);
            vr = *(const short8*)(vb + (size_t)row * 1024 + kt0 + 64 + c8);
        }

        // GEMM1 (swapped): lane holds S^T[kt=t*16+quad*4+r][q'=m15]
        float4_ S[4];
#pragma unroll
        for (int t = 0; t < 4; ++t) S[t] = (float4_){0, 0, 0, 0};
#pragma unroll
        for (int c = 0; c < 2; ++c) {
            short8 kf[4];
#pragma unroll
            for (int t = 0; t < 4; ++t)
                kf[t] = *(const short8*)&Kl[(t * 16 + m15) * 64 +
                                            ((c * 32 + quad * 8) ^ rdsw)];
            __builtin_amdgcn_s_setprio(1);
#pragma unroll
            for (int t = 0; t < 4; ++t)
                S[t] = MFMA16(kf[t], qf[c], S[t]);
            __builtin_amdgcn_s_setprio(0);
        }

        // exp2 + pack (cvt_pk) + b64 cell store; l partial
        {
            float lsum = 0.0f;
#pragma unroll
            for (int t = 0; t < 4; ++t) {
                float p0 = exp2_fast(S[t][0]);
                float p1 = exp2_fast(S[t][1]);
                float p2 = exp2_fast(S[t][2]);
                float p3 = exp2_fast(S[t][3]);
                uint2 st; st.x = cvtpk_bf16(p0, p1); st.y = cvtpk_bf16(p2, p3);
                // cell(pair = t*2 + (quad>>1), col = m15), half = quad&1
                *(uint2*)&Pl[w][t * 2 + (quad >> 1)][m15][(quad & 1) * 4] = st;
                lsum += (p0 + p1) + (p2 + p3);
            }
            lp += lsum;
        }

        // GEMM2: O^T[d][q'] += V^T[d][kt] * P^T[kt][q']
#pragma unroll
        for (int c = 0; c < 2; ++c) {
            short8 av[4];
#pragma unroll
            for (int dt = 0; dt < 4; ++dt)
                av[dt] = *(const short8*)&Vl[(dt * 16 + m15) * 64 +
                                             ((c * 32 + quad * 8) ^ rdsw)];
            short8 bp = *(const short8*)&Pl[w][c * 4 + quad][m15][0];
            __builtin_amdgcn_s_setprio(1);
#pragma unroll
            for (int dt = 0; dt < 4; ++dt)
                O[dt] = MFMA16(av[dt], bp, O[dt]);
            __builtin_amdgcn_s_setprio(0);
        }

        __syncthreads();             // all waves done reading Kl/Vl
        if (more) {                  // write prefetched tile (vmcnt wait here)
            *(short8*)&Kl[row * 64 + stsw] = kr;
            *(short8*)&Vl[row * 64 + stsw] = vr;
            __syncthreads();
        }
    }

    // l: sum the 4 quad partials for column q'=m15 (all lanes end with full l)
    {
        float v = lp;
        v += __shfl_xor(v, 16);
        v += __shfl_xor(v, 32);
        float linv = 1.0f / v;
        int n = q0 + w * 16 + m15;
#pragma unroll
        for (int dt = 0; dt < 4; ++dt) {
            ushort4 st;
            st.x = f2bf(O[dt][0] * linv);
            st.y = f2bf(O[dt][1] * linv);
            st.z = f2bf(O[dt][2] * linv);
            st.w = f2bf(O[dt][3] * linv);
            // in-place over qbuf: [bh][n][64]
            *(ushort4*)&qb[(size_t)n * 64 + dt * 16 + quad * 4] = st;
        }
    }
}

// ---------------------------------------------------------------------------
// Output projection + bias + residual. AO read from qbuf [bh][n][64].
// Grid (16 nt, 4 ft, 16 b). Linear [64][64] tiles + attn-proven XOR swizzle;
// wo conversion via v_cvt_pk_bf16_f32.
// ---------------------------------------------------------------------------
__global__ __launch_bounds__(256) void proj_mfma(
    const u16* __restrict__ ao, const float* __restrict__ wo,
    const float* __restrict__ bo, const float* __restrict__ x,
    float* __restrict__ out)
{
    __shared__ u16 Wl[64 * 64];    // elem(r,c) at r*64 + (c ^ ((r&7)<<3))
    __shared__ u16 Tl[64 * 64];
    const int tid = threadIdx.x;
    const int lane = tid & 63, w = tid >> 6;
    const int quad = lane >> 4, m15 = lane & 15;
    const int n0 = blockIdx.x * 64, f0 = blockIdx.y * 64, b = blockIdx.z;

    float4_ acc[4] = {{0,0,0,0},{0,0,0,0},{0,0,0,0},{0,0,0,0}};
    const int row = tid >> 3, c8 = (tid & 7) * 8;
    const int stsw = c8 ^ ((row & 7) << 3);
    const int rdsw = (m15 & 7) << 3;

    for (int cc0 = 0; cc0 < 512; cc0 += 64) {
        __syncthreads();
        const int h = cc0 >> 6;
#pragma unroll
        for (int rr = 0; rr < 64; rr += 32) {
            const float* wsrc = wo + (size_t)(f0 + row + rr) * 512 + cc0 + c8;
            float4 v0 = *(const float4*)wsrc;
            float4 v1 = *(const float4*)(wsrc + 4);
            uint4 pk;
            pk.x = cvtpk_bf16(v0.x, v0.y);
            pk.y = cvtpk_bf16(v0.z, v0.w);
            pk.z = cvtpk_bf16(v1.x, v1.y);
            pk.w = cvtpk_bf16(v1.z, v1.w);
            *(uint4*)&Wl[(row + rr) * 64 + stsw] = pk;
            *(short8*)&Tl[(row + rr) * 64 + stsw] =
                *(const short8*)(ao + ((size_t)((b << 3) + h) * 1024 + n0 + row + rr) * 64 + c8);
        }
        __syncthreads();
#pragma unroll
        for (int c = 0; c < 2; ++c) {
            short8 af = *(const short8*)&Wl[(w * 16 + m15) * 64 +
                                            ((c * 32 + quad * 8) ^ rdsw)];
#pragma unroll
            for (int t = 0; t < 4; ++t) {
                short8 bf = *(const short8*)&Tl[(t * 16 + m15) * 64 +
                                                ((c * 32 + quad * 8) ^ rdsw)];
                acc[t] = MFMA16(af, bf, acc[t]);
            }
        }
    }

    float bi[4];
#pragma unroll
    for (int r = 0; r < 4; ++r) bi[r] = bo[f0 + w * 16 + quad * 4 + r];
#pragma unroll
    for (int t = 0; t < 4; ++t) {
        int n = n0 + t * 16 + m15;
#pragma unroll
        for (int r = 0; r < 4; ++r) {
            int f = f0 + w * 16 + quad * 4 + r;
            size_t idx = ((size_t)(b * 256) + f) * 1024 + n;
            out[idx] = acc[t][r] + bi[r] + x[idx];
        }
    }
}

extern "C" void kernel_launch(void* const* d_in, const int* in_sizes, int n_in,
                              void* d_out, int out_size, void* d_ws, size_t ws_size,
                              hipStream_t stream) {
    const float* x  = (const float*)d_in[0];
    const float* wq = (const float*)d_in[1];
    const float* bq = (const float*)d_in[2];
    const float* wk = (const float*)d_in[3];
    const float* bk = (const float*)d_in[4];
    const float* wv = (const float*)d_in[5];
    const float* bv = (const float*)d_in[6];
    const float* wo = (const float*)d_in[7];
    const float* bo = (const float*)d_in[8];

    // ws layout (u16 elems), ~59.8 MiB used:
    //   qkvbuf: 3 x 8,388,608 (Q, K, V). attn writes AO in-place over Q.
    //   region: xT[4,194,304] + wb[393,216] — no aliasing with anything live.
    u16* qkvbuf = (u16*)d_ws;
    u16* region = qkvbuf + 3 * 8388608;
    u16* xT = region;
    u16* wb = region + 4194304;

    prep<<<1536, 256, 0, stream>>>(wq, wk, wv, x, wb, xT);

    qkv_mfma<<<dim3(8, 12, 16), 256, 0, stream>>>(
        xT, wb, wq, wk, wv, bq, bk, bv, qkvbuf);

    attn_mfma<<<dim3(128, 8), 512, 0, stream>>>(
        qkvbuf, qkvbuf + 8388608, qkvbuf + 16777216);

    proj_mfma<<<dim3(16, 4, 16), 256, 0, stream>>>(qkvbuf, wo, bo, x, (float*)d_out);
}

// Round 13
// 164.032 us; speedup vs baseline: 1.2202x; 1.0625x over previous
//
#include <hip/hip_runtime.h>

// ResidualAttentionBlock (MFMA, round 20): B=16, FIN=256, H=W=32 (N=1024),
// NH=8, FH=64, CIN=258, COUT=512. Inputs fp32. v_mfma_f32_16x16x32_bf16,
// fp32 accumulation.
//
// Round 20 (attn only; prep/qkv/proj = round 19):
//  - attn is LDS-READ-BOUND: per wave-iter each wave reads full K+V tiles
//    (16KB) + P (2KB) serving only 16 MFMAs. 8192 waves x 16 iters x 18KB
//    = 2.36GB / 69TB/s = 34us = 60% of attn's 56.9us. (Explains why
//    prefetch/barrier tweaks were neutral rounds 16-19.)
//  - Fix: 32 q-rows/wave (2 subs) halves LDS traffic per FLOP. 512-thr
//    8-wave shell, q-tile 256, grid (128 bh, 4 qt). LDS 48KB (Kl 8+Vl 8+
//    Pl 32) -> 3 blocks/CU; round-14's identical per-wave structure
//    measured VGPR=64 -> 8 waves/SIMD legal -> 24 waves/CU (1.5x round 14).
//    No reg-prefetch (neutral, and keeps VGPR<=64). FETCH halves (4 q-blocks
//    per bh instead of 8).
//  - Kept verified pieces: swapped QK^T, exp2 softmax, conflict-free Pl
//    cells, K/V XOR swizzle, XCD-local grid, setprio.

typedef unsigned short u16;
typedef unsigned int   u32;
typedef __attribute__((ext_vector_type(8))) short  short8;
typedef __attribute__((ext_vector_type(4))) float  float4_;

#define MFMA16(a, b, c) __builtin_amdgcn_mfma_f32_16x16x32_bf16(a, b, c, 0, 0, 0)

__device__ __forceinline__ float bf2f(u16 u) {
    union { u32 i; float f; } v; v.i = ((u32)u) << 16; return v.f;
}
__device__ __forceinline__ u16 f2bf(float f) {           // RNE
    union { float f; u32 i; } v; v.f = f;
    u32 r = v.i + 0x7FFFu + ((v.i >> 16) & 1u);
    return (u16)(r >> 16);
}
__device__ __forceinline__ float exp2_fast(float x) {    // 2^x
    float r;
    asm("v_exp_f32 %0, %1" : "=v"(r) : "v"(x));
    return r;
}
__device__ __forceinline__ u32 cvtpk_bf16(float lo, float hi) {  // {bf16(lo), bf16(hi)}
    u32 r;
    asm("v_cvt_pk_bf16_f32 %0, %1, %2" : "=v"(r) : "v"(lo), "v"(hi));
    return r;
}

// ---------------------------------------------------------------------------
// prep: blocks [0,512) convert wq/wk/wv [512][258] fp32 -> wb [1536][256] bf16
//       blocks [512,1536) transpose x [b][256][1024] fp32 -> xT [b][1024][256]
// ---------------------------------------------------------------------------
__global__ __launch_bounds__(256) void prep(
    const float* __restrict__ wq, const float* __restrict__ wk,
    const float* __restrict__ wv, const float* __restrict__ x,
    u16* __restrict__ wb, u16* __restrict__ xT)
{
    __shared__ float Lt[64][65];
    const int bid = blockIdx.x;
    const int tid = threadIdx.x;
    if (bid < 512) {
        int i = bid * 256 + tid;
        int o = i >> 8, c = i & 255;
        size_t si = (size_t)o * 258 + c;
        wb[i]          = f2bf(wq[si]);
        wb[131072 + i] = f2bf(wk[si]);
        wb[262144 + i] = f2bf(wv[si]);
    } else {
        int r = bid - 512;
        int n0 = (r & 15) * 64, c0 = ((r >> 4) & 3) * 64, b = r >> 6;
#pragma unroll
        for (int p = 0; p < 4; ++p) {
            int c = p * 16 + (tid >> 4);
            int nn = (tid & 15) * 4;
            float4 v = *(const float4*)&x[((size_t)(b * 256) + c0 + c) * 1024 + n0 + nn];
            Lt[c][nn + 0] = v.x; Lt[c][nn + 1] = v.y;
            Lt[c][nn + 2] = v.z; Lt[c][nn + 3] = v.w;
        }
        __syncthreads();
#pragma unroll
        for (int p = 0; p < 4; ++p) {
            int n = p * 16 + (tid >> 4);
            int cc = (tid & 15) * 4;
            ushort4 st;
            st.x = f2bf(Lt[cc + 0][n]); st.y = f2bf(Lt[cc + 1][n]);
            st.z = f2bf(Lt[cc + 2][n]); st.w = f2bf(Lt[cc + 3][n]);
            *(ushort4*)&xT[((size_t)(b << 10) + n0 + n) * 256 + c0 + cc] = st;
        }
    }
}

// ---------------------------------------------------------------------------
// Fused QKV GEMM, 128x128 tile, software-pipelined K-step 32 over a [128][64]
// double-parity LDS. Grid (8 nt, 12 mt, 16 b). mat 0=Q token-major
// [bh][n][64]; mat 1=K (pre-scaled 0.125*log2e) token-major; mat 2=V d-major.
// ---------------------------------------------------------------------------
__global__ __launch_bounds__(256) void qkv_mfma(
    const u16* __restrict__ xT, const u16* __restrict__ wb,
    const float* __restrict__ wq, const float* __restrict__ wk,
    const float* __restrict__ wv,
    const float* __restrict__ bq, const float* __restrict__ bk,
    const float* __restrict__ bv,
    u16* __restrict__ qkvbuf)
{
    __shared__ u16 Wl[128 * 64];   // logical (row, lc): phys = row*64 + (lc ^ ((row&7)<<3))
    __shared__ u16 Tl[128 * 64];   // lc in [0,32) = parity 0, [32,64) = parity 1
    const int tid = threadIdx.x;
    const int lane = tid & 63, w = tid >> 6;
    const int quad = lane >> 4, m15 = lane & 15;
    const int n0 = blockIdx.x * 128, mt = blockIdx.y, b = blockIdx.z;
    const int mat = mt >> 2;
    const int m0 = mt * 128;                    // row in combined W
    const float* worig = (mat == 0) ? wq : ((mat == 1) ? wk : wv);
    const float* bias  = (mat == 0) ? bq : ((mat == 1) ? bk : bv);
    const float oscale = (mat == 1) ? 0.1803368801111204f : 1.0f;  // 0.125*log2(e)
    u16* outbuf = qkvbuf + (size_t)mat * 8388608;

    float4_ acc[2][8];
#pragma unroll
    for (int s = 0; s < 2; ++s)
#pragma unroll
        for (int t = 0; t < 8; ++t) acc[s][t] = (float4_){0, 0, 0, 0};

    // staging map: thread covers rows {srow, srow+64}, 8 cols at sc8, both arrays
    const int srow = tid >> 2;                 // 0..63
    const int sc8  = (tid & 3) * 8;            // 0,8,16,24 (within 32-col K-step)
    const int rdsw = (m15 & 7) << 3;           // fragment-read col XOR
    const int sw0  = (srow & 7) << 3;          // staging swizzle, rows srow / srow+64 (same &7)

    const u16* wsrc = wb + (size_t)(m0 + srow) * 256 + sc8;
    const u16* tsrc = xT + ((size_t)(b << 10) + n0 + srow) * 256 + sc8;

    // prologue: stage K-step 0 into parity 0
    {
        short8 w0 = *(const short8*)(wsrc);
        short8 w1 = *(const short8*)(wsrc + 64 * 256);
        short8 t0 = *(const short8*)(tsrc);
        short8 t1 = *(const short8*)(tsrc + 64 * 256);
        *(short8*)&Wl[srow * 64 + (sc8 ^ sw0)]        = w0;
        *(short8*)&Wl[(srow + 64) * 64 + (sc8 ^ sw0)] = w1;
        *(short8*)&Tl[srow * 64 + (sc8 ^ sw0)]        = t0;
        *(short8*)&Tl[(srow + 64) * 64 + (sc8 ^ sw0)] = t1;
    }
    __syncthreads();

#pragma unroll
    for (int k = 0; k < 8; ++k) {
        const int p = k & 1;
        short8 pw0, pw1, pt0, pt1;
        if (k < 7) {                           // issue next-step loads (regs)
            const int kc = (k + 1) * 32;
            pw0 = *(const short8*)(wsrc + kc);
            pw1 = *(const short8*)(wsrc + 64 * 256 + kc);
            pt0 = *(const short8*)(tsrc + kc);
            pt1 = *(const short8*)(tsrc + 64 * 256 + kc);
        }

        // compute step k on parity p (logical col base p*32 + quad*8)
        const int cb = p * 32 + quad * 8;
        short8 af0 = *(const short8*)&Wl[(w * 32 + m15) * 64 + (cb ^ rdsw)];
        short8 af1 = *(const short8*)&Wl[(w * 32 + 16 + m15) * 64 + (cb ^ rdsw)];
        __builtin_amdgcn_s_setprio(1);
#pragma unroll
        for (int t = 0; t < 8; ++t) {
            short8 bf = *(const short8*)&Tl[(t * 16 + m15) * 64 + (cb ^ rdsw)];
            acc[0][t] = MFMA16(af0, bf, acc[0][t]);
            acc[1][t] = MFMA16(af1, bf, acc[1][t]);
        }
        __builtin_amdgcn_s_setprio(0);

        if (k < 7) {                           // write parity p^1 (vmcnt wait here;
            const int pc = (p ^ 1) * 32 + sc8; //  other waves only read parity p)
            *(short8*)&Wl[srow * 64 + (pc ^ sw0)]        = pw0;
            *(short8*)&Wl[(srow + 64) * 64 + (pc ^ sw0)] = pw1;
            *(short8*)&Tl[srow * 64 + (pc ^ sw0)]        = pt0;
            *(short8*)&Tl[(srow + 64) * 64 + (pc ^ sw0)] = pt1;
        }
        __syncthreads();
    }

    // epilogue: rank-2 pos + bias, scale, store. om = row within this mat's 512.
#pragma unroll
    for (int s = 0; s < 2; ++s) {
        float wg[4], wx[4], bi[4];
#pragma unroll
        for (int r = 0; r < 4; ++r) {
            int om = (mt & 3) * 128 + w * 32 + s * 16 + quad * 4 + r;
            wg[r] = worig[(size_t)om * 258 + 256];
            wx[r] = worig[(size_t)om * 258 + 257];
            bi[r] = bias[om];
        }
        const int h = (mt & 3) * 2 + ((w * 32 + s * 16) >> 6);
        const int dbase = ((w * 32 + s * 16) & 63) + quad * 4;
#pragma unroll
        for (int t = 0; t < 8; ++t) {
            int n = n0 + t * 16 + m15;
            float gy = -1.0f + 2.0f * (float)(n >> 5) / 31.0f;
            float gx = -1.0f + 2.0f * (float)(n & 31) / 31.0f;
            float v[4];
#pragma unroll
            for (int r = 0; r < 4; ++r)
                v[r] = (acc[s][t][r] + wg[r] * gy + wx[r] * gx + bi[r]) * oscale;
            if (mat != 2) {      // token-major [bh][n][64]
                ushort4 st;
                st.x = f2bf(v[0]); st.y = f2bf(v[1]);
                st.z = f2bf(v[2]); st.w = f2bf(v[3]);
                *(ushort4*)&outbuf[((size_t)(b * 8 + h) * 1024 + n) * 64 + dbase] = st;
            } else {             // d-major [bh][64][n]
#pragma unroll
                for (int r = 0; r < 4; ++r)
                    outbuf[((size_t)(b * 8 + h) * 64 + dbase + r) * 1024 + n] = f2bf(v[r]);
            }
        }
    }
}

// ---------------------------------------------------------------------------
// Attention (round 20): block = (bh, q-tile 256), 8 waves x 32 q-rows
// (2 subs), 512 threads. Swapped QK^T; exp2 softmax; conflict-free Pl cells;
// l = 1 scalar/sub + 2 shfl_xor. Output in-place over qbuf [bh][n][64].
// Grid (128 bh, 4 qt). LDS 48KB -> 3 blocks/CU; target VGPR<=64 (round-14
// measured 64 for this per-wave structure) -> 24 waves/CU.
// ---------------------------------------------------------------------------
__global__ __launch_bounds__(512) void attn_mfma(
    u16* __restrict__ qbuf, const u16* __restrict__ kbuf,
    const u16* __restrict__ vbuf)
{
    __shared__ u16 Kl[64 * 64];        // [kt][d], elem(kt,d) at kt*64 + (d ^ ((kt&7)<<3))
    __shared__ u16 Vl[64 * 64];        // V^T [d][kt], elem(d,kt) at d*64 + (kt ^ ((d&7)<<3))
    __shared__ u16 Pl[8][2][8][16][8]; // [w][s][pair][col=q'][8 kt] cells

    const int tid = threadIdx.x;
    const int lane = tid & 63, w = tid >> 6;          // w in [0,8)
    const int quad = lane >> 4, m15 = lane & 15;
    const int bh = blockIdx.x;
    const int q0 = blockIdx.y * 256;
    u16* qb = qbuf + (size_t)bh * 65536;
    const u16* kb = kbuf + (size_t)bh * 65536;   // [1024 n][64 d]
    const u16* vb = vbuf + (size_t)bh * 65536;   // [64 d][1024 n]

    // Q frags (B-operand): wave w owns q rows q0 + w*32 + s*16 + [0,16)
    short8 qf[2][2];
#pragma unroll
    for (int s = 0; s < 2; ++s) {
        const u16* qr = qb + (size_t)(q0 + w * 32 + s * 16 + m15) * 64 + quad * 8;
        qf[s][0] = *(const short8*)qr;
        qf[s][1] = *(const short8*)(qr + 32);
    }

    float4_ O[2][4];                 // O^T tiles per sub
    float lp[2] = {0.0f, 0.0f};      // per-lane partial l (one scalar per sub)
#pragma unroll
    for (int s = 0; s < 2; ++s)
#pragma unroll
        for (int t = 0; t < 4; ++t) O[s][t] = (float4_){0, 0, 0, 0};

    const int row = tid >> 3, c8 = (tid & 7) * 8;     // 512 thr cover 64 rows x 64 cols
    const int stsw = c8 ^ ((row & 7) << 3);           // K/V staging col swizzle (u16)
    const int rdsw = (m15 & 7) << 3;                  // K/V fragment-read col XOR (u16)

    for (int kt0 = 0; kt0 < 1024; kt0 += 64) {
        __syncthreads();
        *(short8*)&Kl[row * 64 + stsw] =
            *(const short8*)(kb + (size_t)(kt0 + row) * 64 + c8);
        *(short8*)&Vl[row * 64 + stsw] =
            *(const short8*)(vb + (size_t)row * 1024 + kt0 + c8);
        __syncthreads();

        // GEMM1 (swapped): lane holds S^T[kt=t*16+quad*4+r][q'=m15], per sub
        float4_ S[2][4];
#pragma unroll
        for (int s = 0; s < 2; ++s)
#pragma unroll
            for (int t = 0; t < 4; ++t) S[s][t] = (float4_){0, 0, 0, 0};
#pragma unroll
        for (int c = 0; c < 2; ++c) {
            short8 kf[4];
#pragma unroll
            for (int t = 0; t < 4; ++t)
                kf[t] = *(const short8*)&Kl[(t * 16 + m15) * 64 +
                                            ((c * 32 + quad * 8) ^ rdsw)];
            __builtin_amdgcn_s_setprio(1);
#pragma unroll
            for (int s = 0; s < 2; ++s)
#pragma unroll
                for (int t = 0; t < 4; ++t)
                    S[s][t] = MFMA16(kf[t], qf[s][c], S[s][t]);
            __builtin_amdgcn_s_setprio(0);
        }

        // exp2 + pack (cvt_pk) + b64 cell store; l partial (scalar per sub)
#pragma unroll
        for (int s = 0; s < 2; ++s) {
            float lsum = 0.0f;
#pragma unroll
            for (int t = 0; t < 4; ++t) {
                float p0 = exp2_fast(S[s][t][0]);
                float p1 = exp2_fast(S[s][t][1]);
                float p2 = exp2_fast(S[s][t][2]);
                float p3 = exp2_fast(S[s][t][3]);
                uint2 st; st.x = cvtpk_bf16(p0, p1); st.y = cvtpk_bf16(p2, p3);
                // cell(pair = t*2 + (quad>>1), col = m15), half = quad&1
                *(uint2*)&Pl[w][s][t * 2 + (quad >> 1)][m15][(quad & 1) * 4] = st;
                lsum += (p0 + p1) + (p2 + p3);
            }
            lp[s] += lsum;
        }

        // GEMM2: O^T[d][q'] += V^T[d][kt] * P^T[kt][q'] — av shared across subs
#pragma unroll
        for (int c = 0; c < 2; ++c) {
            short8 av[4];
#pragma unroll
            for (int dt = 0; dt < 4; ++dt)
                av[dt] = *(const short8*)&Vl[(dt * 16 + m15) * 64 +
                                             ((c * 32 + quad * 8) ^ rdsw)];
#pragma unroll
            for (int s = 0; s < 2; ++s) {
                short8 bp = *(const short8*)&Pl[w][s][c * 4 + quad][m15][0];
                __builtin_amdgcn_s_setprio(1);
#pragma unroll
                for (int dt = 0; dt < 4; ++dt)
                    O[s][dt] = MFMA16(av[dt], bp, O[s][dt]);
                __builtin_amdgcn_s_setprio(0);
            }
        }
    }

    // l: sum the 4 quad partials for column q'=m15 (all lanes end with full l)
#pragma unroll
    for (int s = 0; s < 2; ++s) {
        float v = lp[s];
        v += __shfl_xor(v, 16);
        v += __shfl_xor(v, 32);
        float linv = 1.0f / v;
        int n = q0 + w * 32 + s * 16 + m15;
#pragma unroll
        for (int dt = 0; dt < 4; ++dt) {
            ushort4 st;
            st.x = f2bf(O[s][dt][0] * linv);
            st.y = f2bf(O[s][dt][1] * linv);
            st.z = f2bf(O[s][dt][2] * linv);
            st.w = f2bf(O[s][dt][3] * linv);
            // in-place over qbuf: [bh][n][64]
            *(ushort4*)&qb[(size_t)n * 64 + dt * 16 + quad * 4] = st;
        }
    }
}

// ---------------------------------------------------------------------------
// Output projection + bias + residual. AO read from qbuf [bh][n][64].
// Grid (16 nt, 4 ft, 16 b). Linear [64][64] tiles + attn-proven XOR swizzle;
// wo conversion via v_cvt_pk_bf16_f32.
// ---------------------------------------------------------------------------
__global__ __launch_bounds__(256) void proj_mfma(
    const u16* __restrict__ ao, const float* __restrict__ wo,
    const float* __restrict__ bo, const float* __restrict__ x,
    float* __restrict__ out)
{
    __shared__ u16 Wl[64 * 64];    // elem(r,c) at r*64 + (c ^ ((r&7)<<3))
    __shared__ u16 Tl[64 * 64];
    const int tid = threadIdx.x;
    const int lane = tid & 63, w = tid >> 6;
    const int quad = lane >> 4, m15 = lane & 15;
    const int n0 = blockIdx.x * 64, f0 = blockIdx.y * 64, b = blockIdx.z;

    float4_ acc[4] = {{0,0,0,0},{0,0,0,0},{0,0,0,0},{0,0,0,0}};
    const int row = tid >> 3, c8 = (tid & 7) * 8;
    const int stsw = c8 ^ ((row & 7) << 3);
    const int rdsw = (m15 & 7) << 3;

    for (int cc0 = 0; cc0 < 512; cc0 += 64) {
        __syncthreads();
        const int h = cc0 >> 6;
#pragma unroll
        for (int rr = 0; rr < 64; rr += 32) {
            const float* wsrc = wo + (size_t)(f0 + row + rr) * 512 + cc0 + c8;
            float4 v0 = *(const float4*)wsrc;
            float4 v1 = *(const float4*)(wsrc + 4);
            uint4 pk;
            pk.x = cvtpk_bf16(v0.x, v0.y);
            pk.y = cvtpk_bf16(v0.z, v0.w);
            pk.z = cvtpk_bf16(v1.x, v1.y);
            pk.w = cvtpk_bf16(v1.z, v1.w);
            *(uint4*)&Wl[(row + rr) * 64 + stsw] = pk;
            *(short8*)&Tl[(row + rr) * 64 + stsw] =
                *(const short8*)(ao + ((size_t)((b << 3) + h) * 1024 + n0 + row + rr) * 64 + c8);
        }
        __syncthreads();
#pragma unroll
        for (int c = 0; c < 2; ++c) {
            short8 af = *(const short8*)&Wl[(w * 16 + m15) * 64 +
                                            ((c * 32 + quad * 8) ^ rdsw)];
#pragma unroll
            for (int t = 0; t < 4; ++t) {
                short8 bf = *(const short8*)&Tl[(t * 16 + m15) * 64 +
                                                ((c * 32 + quad * 8) ^ rdsw)];
                acc[t] = MFMA16(af, bf, acc[t]);
            }
        }
    }

    float bi[4];
#pragma unroll
    for (int r = 0; r < 4; ++r) bi[r] = bo[f0 + w * 16 + quad * 4 + r];
#pragma unroll
    for (int t = 0; t < 4; ++t) {
        int n = n0 + t * 16 + m15;
#pragma unroll
        for (int r = 0; r < 4; ++r) {
            int f = f0 + w * 16 + quad * 4 + r;
            size_t idx = ((size_t)(b * 256) + f) * 1024 + n;
            out[idx] = acc[t][r] + bi[r] + x[idx];
        }
    }
}

extern "C" void kernel_launch(void* const* d_in, const int* in_sizes, int n_in,
                              void* d_out, int out_size, void* d_ws, size_t ws_size,
                              hipStream_t stream) {
    const float* x  = (const float*)d_in[0];
    const float* wq = (const float*)d_in[1];
    const float* bq = (const float*)d_in[2];
    const float* wk = (const float*)d_in[3];
    const float* bk = (const float*)d_in[4];
    const float* wv = (const float*)d_in[5];
    const float* bv = (const float*)d_in[6];
    const float* wo = (const float*)d_in[7];
    const float* bo = (const float*)d_in[8];

    // ws layout (u16 elems), ~59.8 MiB used:
    //   qkvbuf: 3 x 8,388,608 (Q, K, V). attn writes AO in-place over Q.
    //   region: xT[4,194,304] + wb[393,216] — no aliasing with anything live.
    u16* qkvbuf = (u16*)d_ws;
    u16* region = qkvbuf + 3 * 8388608;
    u16* xT = region;
    u16* wb = region + 4194304;

    prep<<<1536, 256, 0, stream>>>(wq, wk, wv, x, wb, xT);

    qkv_mfma<<<dim3(8, 12, 16), 256, 0, stream>>>(
        xT, wb, wq, wk, wv, bq, bk, bv, qkvbuf);

    attn_mfma<<<dim3(128, 4), 512, 0, stream>>>(
        qkvbuf, qkvbuf + 8388608, qkvbuf + 16777216);

    proj_mfma<<<dim3(16, 4, 16), 256, 0, stream>>>(qkvbuf, wo, bo, x, (float*)d_out);
}